// Round 6
// baseline (157.488 us; speedup 1.0000x reference)
//
#include <hip/hip_runtime.h>

constexpr int D  = 128;   // feature dim (= H*F)
constexpr int NH = 4;     // heads
constexpr int NF = 32;    // features per head

typedef __attribute__((ext_vector_type(8))) short bfrag;   // 8 bf16 = 4 VGPR
typedef __attribute__((ext_vector_type(4))) float ffrag;   // 4 f32 acc

// bf16 RNE helpers
__device__ __forceinline__ unsigned short bf16h(float x) {
    unsigned u = __float_as_uint(x);
    u += 0x7fffu + ((u >> 16) & 1u);
    return (unsigned short)(u >> 16);
}
__device__ __forceinline__ float bf16tof(unsigned short h) {
    return __uint_as_float(((unsigned)h) << 16);
}

// ---- launch 1: wsplit (blocks 0..15) + zero counters (blocks 16..) ----
// wsplit output: 1KB chunks indexed ((L*2+plane)*32 + ct*4 + ks); chunk[lane][i]
// = plane(W[ks*32 + (lane>>4)*8 + i][ct*16 + (lane&15)]). A B-frag is then one
// 16B-per-lane read at chunkbase + lane*16B (global or LDS).
__global__ __launch_bounds__(256) void prep_kernel(
    const float* __restrict__ W1, const float* __restrict__ W2,
    unsigned short* __restrict__ wt, int* __restrict__ cnt, int nz)
{
    if (blockIdx.x < 16) {
        const int L  = blockIdx.x >> 3;
        const int ct = blockIdx.x & 7;
        const float* W = L ? W2 : W1;
        const int ks   = threadIdx.x >> 6;
        const int lane = threadIdx.x & 63;
        const int lg = lane >> 4, lc = lane & 15;
        unsigned short* Hp = wt + ((size_t)(L * 2 + 0) * 32 + ct * 4 + ks) * 512 + lane * 8;
        unsigned short* Lp = wt + ((size_t)(L * 2 + 1) * 32 + ct * 4 + ks) * 512 + lane * 8;
        #pragma unroll
        for (int i = 0; i < 8; ++i) {
            const int k = ks * 32 + lg * 8 + i;
            const int c = ct * 16 + lc;
            const float v = W[(size_t)k * 128 + c];
            const unsigned short hh = bf16h(v);
            Hp[i] = hh;
            Lp[i] = bf16h(v - bf16tof(hh));
        }
    } else {
        const int i4 = ((blockIdx.x - 16) * 256 + threadIdx.x) * 4;
        if (i4 + 3 < nz) {
            *(int4*)&cnt[i4] = {0, 0, 0, 0};
        } else if (i4 < nz) {
            for (int i = i4; i < nz; ++i) cnt[i] = 0;
        }
    }
}

// ---- launch 2: persistent MFMA MLP (weights resident in LDS) + histogram ----
// All prior MLP variants pinned at ~43us: the per-wave 128KB weight stream is
// an L1-miss / L2-hot-set wall (400MB at ~9TB/s). Fix: stage all 4 weight
// planes in LDS ONCE per block (128KB), grid-stride waves over 16-row tiles.
// One __syncthreads total; h1 transpose via per-wave 4.3KB scratch in two
// half-feature passes (pitch 68 u32 -> conflict-free uint4 reads).
// LDS = 131072 + 17408 = 148480 B -> 1 block/CU, 4 waves.
__global__ __launch_bounds__(256) void mlp_hist_kernel(
    const float* __restrict__ X,
    const unsigned short* __restrict__ WF,
    const float* __restrict__ b1, const float* __restrict__ g1, const float* __restrict__ be1,
    const float* __restrict__ b2, const float* __restrict__ g2, const float* __restrict__ be2,
    unsigned short* __restrict__ Q, int N,
    const int* __restrict__ recv, int* __restrict__ cnt, int E, int mlpBlocks)
{
    __shared__ unsigned short Wlds[65536];     // 128 KB: all 4 planes, frag-order
    __shared__ unsigned Scr[4][16 * 68];       // 17408 B: per-wave transpose scratch

    if (blockIdx.x >= mlpBlocks) {
        // ---- histogram role (runs as CUs free up from MLP blocks) ----
        const int tid0   = (blockIdx.x - mlpBlocks) * 256 + threadIdx.x;
        const int stride = (gridDim.x - mlpBlocks) * 256;
        for (int i = tid0; i < E; i += stride) atomicAdd(&cnt[recv[i]], 1);
        return;
    }

    const int tid  = threadIdx.x;
    const int lane = tid & 63;
    const int wave = tid >> 6;
    const int lc   = lane & 15;
    const int lg   = lane >> 4;

    // ---- stage all weights to LDS (once) ----
    #pragma unroll 4
    for (int i = tid; i < 8192; i += 256)
        ((uint4*)Wlds)[i] = ((const uint4*)WF)[i];
    __syncthreads();

    // ---- hoist LN params (loop-invariant) ----
    float b1v[8], g1v[8], t1v[8], b2v[8], g2v[8], t2v[8];
    #pragma unroll
    for (int ct = 0; ct < 8; ++ct) {
        const int col = ct * 16 + lc;
        b1v[ct] = b1[col]; g1v[ct] = g1[col]; t1v[ct] = be1[col];
        b2v[ct] = b2[col]; g2v[ct] = g2[col]; t2v[ct] = be2[col];
    }

    unsigned* scr = Scr[wave];

    const int nwt   = (N + 15) / 16;
    const int gstep = mlpBlocks * 4;

    for (int wt = blockIdx.x * 4 + wave; wt < nwt; wt += gstep) {
        const int n0w = wt * 16;

        bfrag ah[4], al[4];
        // ---- A-frags layer 1: from global X, split in-reg ----
        {
            const int rowx = (n0w + lc < N) ? (n0w + lc) : (N - 1);
            const float* xr = X + (size_t)rowx * 128 + lg * 8;
            #pragma unroll
            for (int ks = 0; ks < 4; ++ks) {
                const float4 a = *(const float4*)&xr[ks * 32];
                const float4 b = *(const float4*)&xr[ks * 32 + 4];
                const float f[8] = {a.x, a.y, a.z, a.w, b.x, b.y, b.z, b.w};
                #pragma unroll
                for (int i = 0; i < 8; ++i) {
                    const unsigned short hh = bf16h(f[i]);
                    ah[ks][i] = (short)hh;
                    al[ks][i] = (short)bf16h(f[i] - bf16tof(hh));
                }
            }
        }

        ffrag acc[8];
        #pragma unroll
        for (int i = 0; i < 8; ++i) acc[i] = (ffrag){0.f, 0.f, 0.f, 0.f};

        // ---- gemm layer 1: B-frags from LDS (hi chunks 0.., lo chunks 32..) ----
        #pragma unroll
        for (int ct = 0; ct < 8; ++ct) {
            const unsigned short* bhp = &Wlds[(0  + ct * 4) * 512 + lane * 8];
            const unsigned short* blp = &Wlds[(32 + ct * 4) * 512 + lane * 8];
            ffrag a = acc[ct];
            #pragma unroll
            for (int ks = 0; ks < 4; ++ks) {
                const bfrag bh = *(const bfrag*)(bhp + ks * 512);
                const bfrag bl = *(const bfrag*)(blp + ks * 512);
                a = __builtin_amdgcn_mfma_f32_16x16x32_bf16(ah[ks], bh, a, 0, 0, 0);
                a = __builtin_amdgcn_mfma_f32_16x16x32_bf16(ah[ks], bl, a, 0, 0, 0);
                a = __builtin_amdgcn_mfma_f32_16x16x32_bf16(al[ks], bh, a, 0, 0, 0);
            }
            acc[ct] = a;
        }

        // ---- LN1 + ReLU -> packed hi|lo u32 (kept in regs) ----
        unsigned pkA[4][4], pkB[4][4];     // [ct 0-3 / 4-7][j]
        #pragma unroll
        for (int j = 0; j < 4; ++j) {
            float t[8], s = 0.f, ss = 0.f;
            #pragma unroll
            for (int ct = 0; ct < 8; ++ct) {
                t[ct] = acc[ct][j] + b1v[ct];
                s += t[ct]; ss += t[ct] * t[ct];
            }
            #pragma unroll
            for (int off = 1; off <= 8; off <<= 1) {
                s  += __shfl_xor(s,  off, 16);
                ss += __shfl_xor(ss, off, 16);
            }
            const float mu   = s * (1.f / 128.f);
            const float var  = fmaxf(ss * (1.f / 128.f) - mu * mu, 0.f);
            const float rstd = rsqrtf(var + 1e-6f);
            #pragma unroll
            for (int ct = 0; ct < 8; ++ct) {
                const float o = fmaxf((t[ct] - mu) * rstd * g1v[ct] + t1v[ct], 0.f);
                const unsigned short hh = bf16h(o);
                const unsigned short ll = bf16h(o - bf16tof(hh));
                const unsigned p = (unsigned)hh | ((unsigned)ll << 16);
                if (ct < 4) pkA[ct][j] = p; else pkB[ct - 4][j] = p;
            }
        }

        // ---- transpose pass A: features 0..63 -> A-frags ks 0,1 ----
        #pragma unroll
        for (int ct = 0; ct < 4; ++ct)
            #pragma unroll
            for (int j = 0; j < 4; ++j)
                scr[(lg * 4 + j) * 68 + ct * 16 + lc] = pkA[ct][j];
        asm volatile("s_waitcnt lgkmcnt(0)" ::: "memory");
        #pragma unroll
        for (int ks = 0; ks < 2; ++ks) {
            const uint4 r0 = *(const uint4*)&scr[lc * 68 + ks * 32 + lg * 8];
            const uint4 r1 = *(const uint4*)&scr[lc * 68 + ks * 32 + lg * 8 + 4];
            const unsigned rr[8] = {r0.x, r0.y, r0.z, r0.w, r1.x, r1.y, r1.z, r1.w};
            #pragma unroll
            for (int i = 0; i < 8; ++i) {
                ah[ks][i] = (short)(rr[i] & 0xffffu);
                al[ks][i] = (short)(rr[i] >> 16);
            }
        }
        asm volatile("" ::: "memory");   // keep pass-B writes below pass-A reads

        // ---- transpose pass B: features 64..127 -> A-frags ks 2,3 ----
        #pragma unroll
        for (int ct = 0; ct < 4; ++ct)
            #pragma unroll
            for (int j = 0; j < 4; ++j)
                scr[(lg * 4 + j) * 68 + ct * 16 + lc] = pkB[ct][j];
        asm volatile("s_waitcnt lgkmcnt(0)" ::: "memory");
        #pragma unroll
        for (int ks = 2; ks < 4; ++ks) {
            const uint4 r0 = *(const uint4*)&scr[lc * 68 + (ks - 2) * 32 + lg * 8];
            const uint4 r1 = *(const uint4*)&scr[lc * 68 + (ks - 2) * 32 + lg * 8 + 4];
            const unsigned rr[8] = {r0.x, r0.y, r0.z, r0.w, r1.x, r1.y, r1.z, r1.w};
            #pragma unroll
            for (int i = 0; i < 8; ++i) {
                ah[ks][i] = (short)(rr[i] & 0xffffu);
                al[ks][i] = (short)(rr[i] >> 16);
            }
        }
        asm volatile("" ::: "memory");   // keep next-iter writes below these reads

        // ---- gemm layer 2 (hi chunks 64.., lo chunks 96..) ----
        #pragma unroll
        for (int i = 0; i < 8; ++i) acc[i] = (ffrag){0.f, 0.f, 0.f, 0.f};
        #pragma unroll
        for (int ct = 0; ct < 8; ++ct) {
            const unsigned short* bhp = &Wlds[(64 + ct * 4) * 512 + lane * 8];
            const unsigned short* blp = &Wlds[(96 + ct * 4) * 512 + lane * 8];
            ffrag a = acc[ct];
            #pragma unroll
            for (int ks = 0; ks < 4; ++ks) {
                const bfrag bh = *(const bfrag*)(bhp + ks * 512);
                const bfrag bl = *(const bfrag*)(blp + ks * 512);
                a = __builtin_amdgcn_mfma_f32_16x16x32_bf16(ah[ks], bh, a, 0, 0, 0);
                a = __builtin_amdgcn_mfma_f32_16x16x32_bf16(ah[ks], bl, a, 0, 0, 0);
                a = __builtin_amdgcn_mfma_f32_16x16x32_bf16(al[ks], bh, a, 0, 0, 0);
            }
            acc[ct] = a;
        }

        // ---- LN2 + ReLU -> bf16 q (global) ----
        #pragma unroll
        for (int j = 0; j < 4; ++j) {
            float t[8], s = 0.f, ss = 0.f;
            #pragma unroll
            for (int ct = 0; ct < 8; ++ct) {
                t[ct] = acc[ct][j] + b2v[ct];
                s += t[ct]; ss += t[ct] * t[ct];
            }
            #pragma unroll
            for (int off = 1; off <= 8; off <<= 1) {
                s  += __shfl_xor(s,  off, 16);
                ss += __shfl_xor(ss, off, 16);
            }
            const float mu   = s * (1.f / 128.f);
            const float var  = fmaxf(ss * (1.f / 128.f) - mu * mu, 0.f);
            const float rstd = rsqrtf(var + 1e-6f);
            const int grow = n0w + lg * 4 + j;
            if (grow < N) {
                #pragma unroll
                for (int ct = 0; ct < 8; ++ct) {
                    const float o = fmaxf((t[ct] - mu) * rstd * g2v[ct] + t2v[ct], 0.f);
                    Q[(size_t)grow * 128 + ct * 16 + lc] = bf16h(o);
                }
            }
        }
    }
}

// ---- launch 3: full CSR scan in ONE kernel (last-block-finalizes) ----
__global__ __launch_bounds__(256) void scan_fused_kernel(
    const int* __restrict__ cnt, int* __restrict__ rowptr,
    int* __restrict__ cursor, int* __restrict__ bsum,
    int* __restrict__ done, int N, int E)
{
    __shared__ int lds[256];
    __shared__ int base_s[64];
    __shared__ int amlast;
    const int tid = threadIdx.x;
    const int nb  = gridDim.x;
    const int base = blockIdx.x * 1024 + tid * 4;
    int v0 = (base + 0 < N) ? cnt[base + 0] : 0;
    int v1 = (base + 1 < N) ? cnt[base + 1] : 0;
    int v2 = (base + 2 < N) ? cnt[base + 2] : 0;
    int v3 = (base + 3 < N) ? cnt[base + 3] : 0;
    const int tsum = v0 + v1 + v2 + v3;
    lds[tid] = tsum;
    __syncthreads();
    for (int off = 1; off < 256; off <<= 1) {
        int t = (tid >= off) ? lds[tid - off] : 0;
        __syncthreads();
        lds[tid] += t;
        __syncthreads();
    }
    int run = lds[tid] - tsum;
    if (base + 0 < N) rowptr[base + 0] = run;
    run += v0;
    if (base + 1 < N) rowptr[base + 1] = run;
    run += v1;
    if (base + 2 < N) rowptr[base + 2] = run;
    run += v2;
    if (base + 3 < N) rowptr[base + 3] = run;
    if (tid == 255) bsum[blockIdx.x] = lds[255];

    __threadfence();
    __syncthreads();
    if (tid == 0) amlast = (atomicAdd(done, 1) == nb - 1);
    __syncthreads();
    if (!amlast) return;
    __threadfence();

    if (tid < 64) {
        const int own = (tid < nb) ? bsum[tid] : 0;
        int incl = own;
        #pragma unroll
        for (int off = 1; off < 64; off <<= 1) {
            const int t = __shfl_up(incl, off, 64);
            if (tid >= off) incl += t;
        }
        base_s[tid] = incl - own;
    }
    __syncthreads();

    for (int i = tid * 4; i + 3 < N; i += 1024) {
        const int b4 = base_s[i >> 10];
        int4 r = *(int4*)&rowptr[i];
        r.x += b4; r.y += b4; r.z += b4; r.w += b4;
        *(int4*)&rowptr[i] = r;
        *(int4*)&cursor[i] = r;
    }
    for (int i = (N & ~3) + tid; i < N; i += 256) {
        const int v = rowptr[i] + base_s[i >> 10];
        rowptr[i] = v;
        cursor[i] = v;
    }
    if (tid == 0) rowptr[N] = E;
}

// ---- launch 4: bucket-fill sorted sender ids ----
__global__ __launch_bounds__(256) void fill_kernel(
    const int* __restrict__ senders, const int* __restrict__ receivers,
    int* __restrict__ cursor, int* __restrict__ ssend, int E)
{
    int e = blockIdx.x * blockDim.x + threadIdx.x;
    if (e < E) {
        int r = receivers[e];
        int pos = atomicAdd(&cursor[r], 1);
        ssend[pos] = senders[e];
    }
}

// ---- launch 5: fused per-node attention (bf16 q) ----
__global__ __launch_bounds__(256) void node_attn_kernel(
    const unsigned short* __restrict__ q, const int* __restrict__ rowptr,
    const int* __restrict__ ssend, float* __restrict__ out, int N)
{
    const int lane = threadIdx.x & 63;
    const int hl   = lane & 31;
    const int half = lane >> 5;
    const int wid  = (blockIdx.x * blockDim.x + threadIdx.x) >> 6;
    const int nw   = (gridDim.x * blockDim.x) >> 6;

    for (int n = wid; n < N; n += nw) {
        const uint2 braw = *(const uint2*)&q[(size_t)n * D + hl * 4];
        const float b0 = __uint_as_float(braw.x << 16);
        const float b1 = __uint_as_float(braw.x & 0xffff0000u);
        const float b2 = __uint_as_float(braw.y << 16);
        const float b3 = __uint_as_float(braw.y & 0xffff0000u);

        const int beg = rowptr[n], end = rowptr[n + 1];
        float m = -1e30f, l = 0.f;
        float c0 = 0.f, c1 = 0.f, c2 = 0.f, c3 = 0.f;

        int j = beg + half;
        uint2 raw = {0u, 0u};
        if (j < end)
            raw = *(const uint2*)&q[(size_t)ssend[j] * D + hl * 4];
        for (; j < end; j += 2) {
            const uint2 cur = raw;
            if (j + 2 < end)
                raw = *(const uint2*)&q[(size_t)ssend[j + 2] * D + hl * 4];
            const float a0 = __uint_as_float(cur.x << 16);
            const float a1 = __uint_as_float(cur.x & 0xffff0000u);
            const float a2 = __uint_as_float(cur.y << 16);
            const float a3 = __uint_as_float(cur.y & 0xffff0000u);
            float p = a0 * b0 + a1 * b1 + a2 * b2 + a3 * b3;
            p += __shfl_xor(p, 1);
            p += __shfl_xor(p, 2);
            p += __shfl_xor(p, 4);
            const float logit = p * 0.17677669529663687f;   // 1/sqrt(32)
            const float nm = fmaxf(m, logit);
            const float sc = __expf(m - nm);
            const float u  = __expf(logit - nm);
            l  = l * sc + u;
            c0 = c0 * sc + u * a0;
            c1 = c1 * sc + u * a1;
            c2 = c2 * sc + u * a2;
            c3 = c3 * sc + u * a3;
            m = nm;
        }

        const float om  = __shfl_xor(m, 32);
        const float ol  = __shfl_xor(l, 32);
        const float oc0 = __shfl_xor(c0, 32);
        const float oc1 = __shfl_xor(c1, 32);
        const float oc2 = __shfl_xor(c2, 32);
        const float oc3 = __shfl_xor(c3, 32);
        const float nm = fmaxf(m, om);
        const float s0 = __expf(m - nm), s1 = __expf(om - nm);
        const float lt = l * s0 + ol * s1;
        const float inv = (lt > 0.f) ? (1.f / lt) : 0.f;
        float r0 = fmaxf((c0 * s0 + oc0 * s1) * inv, 0.f);
        float r1 = fmaxf((c1 * s0 + oc1 * s1) * inv, 0.f);
        float r2 = fmaxf((c2 * s0 + oc2 * s1) * inv, 0.f);
        float r3 = fmaxf((c3 * s0 + oc3 * s1) * inv, 0.f);

        r0 += __shfl_xor(r0, 8);  r0 += __shfl_xor(r0, 16);
        r1 += __shfl_xor(r1, 8);  r1 += __shfl_xor(r1, 16);
        r2 += __shfl_xor(r2, 8);  r2 += __shfl_xor(r2, 16);
        r3 += __shfl_xor(r3, 8);  r3 += __shfl_xor(r3, 16);
        if (lane < 8) {
            float4 o = {0.25f * r0, 0.25f * r1, 0.25f * r2, 0.25f * r3};
            *(float4*)&out[(size_t)n * NF + lane * 4] = o;
        }
    }
}

extern "C" void kernel_launch(void* const* d_in, const int* in_sizes, int n_in,
                              void* d_out, int out_size, void* d_ws, size_t ws_size,
                              hipStream_t stream)
{
    const float* nodes = (const float*)d_in[0];
    const float* W1    = (const float*)d_in[1];
    const float* b1    = (const float*)d_in[2];
    const float* g1    = (const float*)d_in[3];
    const float* be1   = (const float*)d_in[4];
    const float* W2    = (const float*)d_in[5];
    const float* b2    = (const float*)d_in[6];
    const float* g2    = (const float*)d_in[7];
    const float* be2   = (const float*)d_in[8];
    const int* senders   = (const int*)d_in[9];
    const int* receivers = (const int*)d_in[10];

    const int N = in_sizes[0] / D;
    const int E = in_sizes[9];
    float* out = (float*)d_out;

    char* ws = (char*)d_ws;
    unsigned short* qb = (unsigned short*)ws; ws += (size_t)N * D * 2;
    unsigned short* wt = (unsigned short*)ws; ws += 4 * 128 * 128 * 2;
    int* cnt      = (int*)ws;    ws += (size_t)(N + 16) * 4;   // +ticket word
    int* rowptr   = (int*)ws;    ws += (size_t)(N + 2) * 4;
    int* cursor   = (int*)ws;    ws += (size_t)N * 4;
    int* bsum     = (int*)ws;    ws += 256 * 4;
    int* ssend    = (int*)ws;    ws += (size_t)E * 4;
    int* done     = cnt + N;                                   // zeroed with cnt

    const int nz = N + 16;
    const int zb = (nz + 1023) / 1024;
    const int nwt = (N + 15) / 16;
    const int mlpBlocks = (nwt + 3) / 4 < 256 ? (nwt + 3) / 4 : 256;
    const int nb = (N + 1023) / 1024;

    // 1: weight split + counter/ticket zero
    prep_kernel<<<16 + zb, 256, 0, stream>>>(W1, W2, wt, cnt, nz);

    // 2: persistent LDS-weight MFMA MLP + edge histogram (tail blocks)
    mlp_hist_kernel<<<mlpBlocks + 128, 256, 0, stream>>>(
        nodes, wt, b1, g1, be1, b2, g2, be2, qb, N,
        receivers, cnt, E, mlpBlocks);

    // 3: single-launch scan -> rowptr + cursor
    scan_fused_kernel<<<nb, 256, 0, stream>>>(cnt, rowptr, cursor, bsum, done, N, E);

    // 4: bucket-fill receiver-sorted sender list
    fill_kernel<<<(E + 255) / 256, 256, 0, stream>>>(senders, receivers, cursor, ssend, E);

    // 5: fused attention + epilogue
    node_attn_kernel<<<(N + 3) / 4, 256, 0, stream>>>(qb, rowptr, ssend, out, N);
}

// Round 7
// 136.627 us; speedup vs baseline: 1.1527x; 1.1527x over previous
//
#include <hip/hip_runtime.h>

constexpr int D  = 128;   // feature dim (= H*F)
constexpr int NH = 4;     // heads
constexpr int NF = 32;    // features per head

typedef __attribute__((ext_vector_type(8))) short bfrag;   // 8 bf16 = 4 VGPR
typedef __attribute__((ext_vector_type(4))) float ffrag;   // 4 f32 acc

// bf16 RNE helpers
__device__ __forceinline__ unsigned short bf16h(float x) {
    unsigned u = __float_as_uint(x);
    u += 0x7fffu + ((u >> 16) & 1u);
    return (unsigned short)(u >> 16);
}
__device__ __forceinline__ float bf16tof(unsigned short h) {
    return __uint_as_float(((unsigned)h) << 16);
}

// ---- zero the histogram counters ----
__global__ __launch_bounds__(256) void zero_cnt_kernel(int* __restrict__ p, int n)
{
    const int i4 = (blockIdx.x * blockDim.x + threadIdx.x) * 4;
    if (i4 + 3 < n) {
        *(int4*)&p[i4] = {0, 0, 0, 0};
    } else if (i4 < n) {
        for (int i = i4; i < n; ++i) p[i] = 0;
    }
}

// ---- one-time: split W1,W2 into bf16 hi/lo planes, FRAGMENT-ORDERED ----
// 1KB chunks indexed ((L*2+plane)*32 + ctg*4 + ks); chunk[lane][i] =
// plane(W[ks*32 + (lane>>4)*8 + i][ctg*16 + (lane&15)]). A B-frag load is one
// coalesced global_load_dwordx4 at chunkbase + lane*16B.
__global__ __launch_bounds__(256) void wsplit_kernel(
    const float* __restrict__ W1, const float* __restrict__ W2,
    unsigned short* __restrict__ wt)
{
    const int L  = blockIdx.x >> 3;          // 16 blocks: L in {0,1}, ctg in 0..7
    const int ct = blockIdx.x & 7;
    const float* W = L ? W2 : W1;
    const int ks   = threadIdx.x >> 6;
    const int lane = threadIdx.x & 63;
    const int lg = lane >> 4, lc = lane & 15;
    unsigned short* Hp = wt + ((size_t)(L * 2 + 0) * 32 + ct * 4 + ks) * 512 + lane * 8;
    unsigned short* Lp = wt + ((size_t)(L * 2 + 1) * 32 + ct * 4 + ks) * 512 + lane * 8;
    #pragma unroll
    for (int i = 0; i < 8; ++i) {
        const int k = ks * 32 + lg * 8 + i;
        const int c = ct * 16 + lc;
        const float v = W[(size_t)k * 128 + c];
        const unsigned short hh = bf16h(v);
        Hp[i] = hh;
        Lp[i] = bf16h(v - bf16tof(hh));
    }
}

// ---- MFMA MLP, column-split pairs ----
// Latency model (R3/R5/R6 fit): MLP time ~ 1/resident-waves; per-wave chain is
// the limiter. So: 2 waves per 16-row tile (wave w owns cols w*64..w*64+63) ->
// 6250 waves (2x), half the per-wave chain; split accumulators (accH/accX)
// break the 3-deep MFMA dependency per ks. Pair exchange (LN sums + h1) via
// 17.4KB LDS, 3 barriers per tile. VGPR target ~110 under (256,4) cap 128.
__global__ __launch_bounds__(256, 4) void mlp_pair_kernel(
    const float* __restrict__ X,
    const unsigned short* __restrict__ WF,
    const float* __restrict__ b1, const float* __restrict__ g1, const float* __restrict__ be1,
    const float* __restrict__ b2, const float* __restrict__ g2, const float* __restrict__ be2,
    unsigned short* __restrict__ Q, int N)
{
    constexpr int PW = 132;                    // u32 pitch
    __shared__ unsigned Scr[2][16 * PW];       // per-pair packed h1 (hi|lo u32)
    __shared__ float Sums[2][2][16][2];        // [pair][wavehalf][row][s,ss]

    const int tid  = threadIdx.x;
    const int lane = tid & 63;
    const int wave = tid >> 6;
    const int pair = wave >> 1;
    const int w    = wave & 1;                 // column half: cols w*64..w*64+63
    const int lc   = lane & 15;
    const int lg   = lane >> 4;

    const int nwt = (N + 15) >> 4;
    const int tileIdx = blockIdx.x * 2 + pair;
    const bool valid = tileIdx < nwt;
    const int n0w = (valid ? tileIdx : (nwt - 1)) * 16;

    // ---- LN params for this wave's 4 col-tiles (ctg = w*4+ct) ----
    float b1v[4], g1v[4], t1v[4], b2v[4], g2v[4], t2v[4];
    #pragma unroll
    for (int ct = 0; ct < 4; ++ct) {
        const int col = (w * 4 + ct) * 16 + lc;
        b1v[ct] = b1[col]; g1v[ct] = g1[col]; t1v[ct] = be1[col];
        b2v[ct] = b2[col]; g2v[ct] = g2[col]; t2v[ct] = be2[col];
    }

    // ---- A-frags layer 1: from global X, split in-reg ----
    bfrag ah[4], al[4];
    {
        const int rowx = (n0w + lc < N) ? (n0w + lc) : (N - 1);
        const float* xr = X + (size_t)rowx * 128 + lg * 8;
        #pragma unroll
        for (int ks = 0; ks < 4; ++ks) {
            const float4 a = *(const float4*)&xr[ks * 32];
            const float4 b = *(const float4*)&xr[ks * 32 + 4];
            const float f[8] = {a.x, a.y, a.z, a.w, b.x, b.y, b.z, b.w};
            #pragma unroll
            for (int i = 0; i < 8; ++i) {
                const unsigned short hh = bf16h(f[i]);
                ah[ks][i] = (short)hh;
                al[ks][i] = (short)bf16h(f[i] - bf16tof(hh));
            }
        }
    }

    ffrag accH[4], accX[4];

    // ---- gemm layer 1: 4 col-tiles, split accumulator chains ----
    #pragma unroll
    for (int ct = 0; ct < 4; ++ct) {
        const int ctg = w * 4 + ct;
        const unsigned short* bhp = WF + (size_t)(0  + ctg * 4) * 512 + lane * 8;
        const unsigned short* blp = WF + (size_t)(32 + ctg * 4) * 512 + lane * 8;
        ffrag aH = (ffrag){0.f, 0.f, 0.f, 0.f};
        ffrag aX = (ffrag){0.f, 0.f, 0.f, 0.f};
        #pragma unroll
        for (int ks = 0; ks < 4; ++ks) {
            const bfrag bh = *(const bfrag*)(bhp + ks * 512);
            const bfrag bl = *(const bfrag*)(blp + ks * 512);
            aH = __builtin_amdgcn_mfma_f32_16x16x32_bf16(ah[ks], bh, aH, 0, 0, 0);
            aX = __builtin_amdgcn_mfma_f32_16x16x32_bf16(ah[ks], bl, aX, 0, 0, 0);
            aX = __builtin_amdgcn_mfma_f32_16x16x32_bf16(al[ks], bh, aX, 0, 0, 0);
        }
        accH[ct] = aH; accX[ct] = aX;
    }

    // ---- LN1 partial sums (this wave's 64 cols) ----
    float tv[4][4];                            // [j][ct]
    #pragma unroll
    for (int j = 0; j < 4; ++j) {
        float s = 0.f, ss = 0.f;
        #pragma unroll
        for (int ct = 0; ct < 4; ++ct) {
            const float t = accH[ct][j] + accX[ct][j] + b1v[ct];
            tv[j][ct] = t;
            s += t; ss += t * t;
        }
        #pragma unroll
        for (int off = 1; off <= 8; off <<= 1) {
            s  += __shfl_xor(s,  off, 16);
            ss += __shfl_xor(ss, off, 16);
        }
        if (lc == 0) {
            Sums[pair][w][lg * 4 + j][0] = s;
            Sums[pair][w][lg * 4 + j][1] = ss;
        }
    }
    __syncthreads();                           // partials visible to partner

    // ---- LN1 finalize + pack h1 into pair scratch ----
    #pragma unroll
    for (int j = 0; j < 4; ++j) {
        const int row = lg * 4 + j;
        const float s  = Sums[pair][0][row][0] + Sums[pair][1][row][0];
        const float ss = Sums[pair][0][row][1] + Sums[pair][1][row][1];
        const float mu   = s * (1.f / 128.f);
        const float var  = fmaxf(ss * (1.f / 128.f) - mu * mu, 0.f);
        const float rstd = rsqrtf(var + 1e-6f);
        #pragma unroll
        for (int ct = 0; ct < 4; ++ct) {
            const float o = fmaxf((tv[j][ct] - mu) * rstd * g1v[ct] + t1v[ct], 0.f);
            const unsigned short hh = bf16h(o);
            const unsigned short ll = bf16h(o - bf16tof(hh));
            Scr[pair][row * PW + (w * 4 + ct) * 16 + lc] =
                (unsigned)hh | ((unsigned)ll << 16);
        }
    }
    __syncthreads();                           // full h1 tile visible

    // ---- A-frags layer 2: full K from pair scratch ----
    #pragma unroll
    for (int ks = 0; ks < 4; ++ks) {
        const uint4 r0 = *(const uint4*)&Scr[pair][lc * PW + ks * 32 + lg * 8];
        const uint4 r1 = *(const uint4*)&Scr[pair][lc * PW + ks * 32 + lg * 8 + 4];
        const unsigned rr[8] = {r0.x, r0.y, r0.z, r0.w, r1.x, r1.y, r1.z, r1.w};
        #pragma unroll
        for (int i = 0; i < 8; ++i) {
            ah[ks][i] = (short)(rr[i] & 0xffffu);
            al[ks][i] = (short)(rr[i] >> 16);
        }
    }

    // ---- gemm layer 2 ----
    #pragma unroll
    for (int ct = 0; ct < 4; ++ct) {
        const int ctg = w * 4 + ct;
        const unsigned short* bhp = WF + (size_t)(64 + ctg * 4) * 512 + lane * 8;
        const unsigned short* blp = WF + (size_t)(96 + ctg * 4) * 512 + lane * 8;
        ffrag aH = (ffrag){0.f, 0.f, 0.f, 0.f};
        ffrag aX = (ffrag){0.f, 0.f, 0.f, 0.f};
        #pragma unroll
        for (int ks = 0; ks < 4; ++ks) {
            const bfrag bh = *(const bfrag*)(bhp + ks * 512);
            const bfrag bl = *(const bfrag*)(blp + ks * 512);
            aH = __builtin_amdgcn_mfma_f32_16x16x32_bf16(ah[ks], bh, aH, 0, 0, 0);
            aX = __builtin_amdgcn_mfma_f32_16x16x32_bf16(ah[ks], bl, aX, 0, 0, 0);
            aX = __builtin_amdgcn_mfma_f32_16x16x32_bf16(al[ks], bh, aX, 0, 0, 0);
        }
        accH[ct] = aH; accX[ct] = aX;
    }

    // ---- LN2 partial sums ----
    #pragma unroll
    for (int j = 0; j < 4; ++j) {
        float s = 0.f, ss = 0.f;
        #pragma unroll
        for (int ct = 0; ct < 4; ++ct) {
            const float t = accH[ct][j] + accX[ct][j] + b2v[ct];
            tv[j][ct] = t;
            s += t; ss += t * t;
        }
        #pragma unroll
        for (int off = 1; off <= 8; off <<= 1) {
            s  += __shfl_xor(s,  off, 16);
            ss += __shfl_xor(ss, off, 16);
        }
        if (lc == 0) {
            Sums[pair][w][lg * 4 + j][0] = s;
            Sums[pair][w][lg * 4 + j][1] = ss;
        }
    }
    __syncthreads();                           // LN2 partials visible

    // ---- LN2 finalize + store bf16 q ----
    #pragma unroll
    for (int j = 0; j < 4; ++j) {
        const int row = lg * 4 + j;
        const float s  = Sums[pair][0][row][0] + Sums[pair][1][row][0];
        const float ss = Sums[pair][0][row][1] + Sums[pair][1][row][1];
        const float mu   = s * (1.f / 128.f);
        const float var  = fmaxf(ss * (1.f / 128.f) - mu * mu, 0.f);
        const float rstd = rsqrtf(var + 1e-6f);
        const int grow = n0w + row;
        if (valid && grow < N) {
            #pragma unroll
            for (int ct = 0; ct < 4; ++ct) {
                const float o = fmaxf((tv[j][ct] - mu) * rstd * g2v[ct] + t2v[ct], 0.f);
                Q[(size_t)grow * 128 + (w * 4 + ct) * 16 + lc] = bf16h(o);
            }
        }
    }
}

// ---- CSR build: histogram ----
__global__ __launch_bounds__(256) void hist_kernel(
    const int* __restrict__ recv, int* __restrict__ cnt, int E)
{
    int i = blockIdx.x * blockDim.x + threadIdx.x;
    if (i < E) atomicAdd(&cnt[recv[i]], 1);
}

// ---- CSR build: per-1024-chunk exclusive scan ----
__global__ __launch_bounds__(256) void scan_blocks_kernel(
    const int* __restrict__ cnt, int* __restrict__ rowptr,
    int* __restrict__ bsum, int N)
{
    __shared__ int lds[256];
    const int tid = threadIdx.x;
    const int base = blockIdx.x * 1024 + tid * 4;
    int v0 = (base + 0 < N) ? cnt[base + 0] : 0;
    int v1 = (base + 1 < N) ? cnt[base + 1] : 0;
    int v2 = (base + 2 < N) ? cnt[base + 2] : 0;
    int v3 = (base + 3 < N) ? cnt[base + 3] : 0;
    const int tsum = v0 + v1 + v2 + v3;
    lds[tid] = tsum;
    __syncthreads();
    for (int off = 1; off < 256; off <<= 1) {
        int t = (tid >= off) ? lds[tid - off] : 0;
        __syncthreads();
        lds[tid] += t;
        __syncthreads();
    }
    int run = lds[tid] - tsum;
    if (base + 0 < N) rowptr[base + 0] = run;
    run += v0;
    if (base + 1 < N) rowptr[base + 1] = run;
    run += v1;
    if (base + 2 < N) rowptr[base + 2] = run;
    run += v2;
    if (base + 3 < N) rowptr[base + 3] = run;
    if (tid == 255) bsum[blockIdx.x] = lds[255];
}

// ---- CSR build: scan block sums ----
__global__ __launch_bounds__(256) void scan_top_kernel(int* bsum, int nb)
{
    __shared__ int lds[256];
    const int tid = threadIdx.x;
    int v = (tid < nb) ? bsum[tid] : 0;
    lds[tid] = v;
    __syncthreads();
    for (int off = 1; off < 256; off <<= 1) {
        int t = (tid >= off) ? lds[tid - off] : 0;
        __syncthreads();
        lds[tid] += t;
        __syncthreads();
    }
    if (tid < nb) bsum[tid] = lds[tid] - v;
}

// ---- CSR build: add chunk offsets ----
__global__ __launch_bounds__(256) void scan_add_kernel(
    int* __restrict__ rowptr, int* __restrict__ cursor,
    const int* __restrict__ bsum, int N, int E)
{
    int i = blockIdx.x * blockDim.x + threadIdx.x;
    if (i < N) {
        int v = rowptr[i] + bsum[i >> 10];
        rowptr[i] = v;
        cursor[i] = v;
    }
    if (i == 0) rowptr[N] = E;
}

// ---- CSR build: bucket-fill sorted sender ids ----
__global__ __launch_bounds__(256) void fill_kernel(
    const int* __restrict__ senders, const int* __restrict__ receivers,
    int* __restrict__ cursor, int* __restrict__ ssend, int E)
{
    int e = blockIdx.x * blockDim.x + threadIdx.x;
    if (e < E) {
        int r = receivers[e];
        int pos = atomicAdd(&cursor[r], 1);
        ssend[pos] = senders[e];
    }
}

// ---- fused per-node attention (bf16 q) ----
__global__ __launch_bounds__(256) void node_attn_kernel(
    const unsigned short* __restrict__ q, const int* __restrict__ rowptr,
    const int* __restrict__ ssend, float* __restrict__ out, int N)
{
    const int lane = threadIdx.x & 63;
    const int hl   = lane & 31;
    const int half = lane >> 5;
    const int wid  = (blockIdx.x * blockDim.x + threadIdx.x) >> 6;
    const int nw   = (gridDim.x * blockDim.x) >> 6;

    for (int n = wid; n < N; n += nw) {
        const uint2 braw = *(const uint2*)&q[(size_t)n * D + hl * 4];
        const float b0 = __uint_as_float(braw.x << 16);
        const float b1 = __uint_as_float(braw.x & 0xffff0000u);
        const float b2 = __uint_as_float(braw.y << 16);
        const float b3 = __uint_as_float(braw.y & 0xffff0000u);

        const int beg = rowptr[n], end = rowptr[n + 1];
        float m = -1e30f, l = 0.f;
        float c0 = 0.f, c1 = 0.f, c2 = 0.f, c3 = 0.f;

        int j = beg + half;
        uint2 raw = {0u, 0u};
        if (j < end)
            raw = *(const uint2*)&q[(size_t)ssend[j] * D + hl * 4];
        for (; j < end; j += 2) {
            const uint2 cur = raw;
            if (j + 2 < end)
                raw = *(const uint2*)&q[(size_t)ssend[j + 2] * D + hl * 4];
            const float a0 = __uint_as_float(cur.x << 16);
            const float a1 = __uint_as_float(cur.x & 0xffff0000u);
            const float a2 = __uint_as_float(cur.y << 16);
            const float a3 = __uint_as_float(cur.y & 0xffff0000u);
            float p = a0 * b0 + a1 * b1 + a2 * b2 + a3 * b3;
            p += __shfl_xor(p, 1);
            p += __shfl_xor(p, 2);
            p += __shfl_xor(p, 4);
            const float logit = p * 0.17677669529663687f;   // 1/sqrt(32)
            const float nm = fmaxf(m, logit);
            const float sc = __expf(m - nm);
            const float u  = __expf(logit - nm);
            l  = l * sc + u;
            c0 = c0 * sc + u * a0;
            c1 = c1 * sc + u * a1;
            c2 = c2 * sc + u * a2;
            c3 = c3 * sc + u * a3;
            m = nm;
        }

        const float om  = __shfl_xor(m, 32);
        const float ol  = __shfl_xor(l, 32);
        const float oc0 = __shfl_xor(c0, 32);
        const float oc1 = __shfl_xor(c1, 32);
        const float oc2 = __shfl_xor(c2, 32);
        const float oc3 = __shfl_xor(c3, 32);
        const float nm = fmaxf(m, om);
        const float s0 = __expf(m - nm), s1 = __expf(om - nm);
        const float lt = l * s0 + ol * s1;
        const float inv = (lt > 0.f) ? (1.f / lt) : 0.f;
        float r0 = fmaxf((c0 * s0 + oc0 * s1) * inv, 0.f);
        float r1 = fmaxf((c1 * s0 + oc1 * s1) * inv, 0.f);
        float r2 = fmaxf((c2 * s0 + oc2 * s1) * inv, 0.f);
        float r3 = fmaxf((c3 * s0 + oc3 * s1) * inv, 0.f);

        r0 += __shfl_xor(r0, 8);  r0 += __shfl_xor(r0, 16);
        r1 += __shfl_xor(r1, 8);  r1 += __shfl_xor(r1, 16);
        r2 += __shfl_xor(r2, 8);  r2 += __shfl_xor(r2, 16);
        r3 += __shfl_xor(r3, 8);  r3 += __shfl_xor(r3, 16);
        if (lane < 8) {
            float4 o = {0.25f * r0, 0.25f * r1, 0.25f * r2, 0.25f * r3};
            *(float4*)&out[(size_t)n * NF + lane * 4] = o;
        }
    }
}

extern "C" void kernel_launch(void* const* d_in, const int* in_sizes, int n_in,
                              void* d_out, int out_size, void* d_ws, size_t ws_size,
                              hipStream_t stream)
{
    const float* nodes = (const float*)d_in[0];
    const float* W1    = (const float*)d_in[1];
    const float* b1    = (const float*)d_in[2];
    const float* g1    = (const float*)d_in[3];
    const float* be1   = (const float*)d_in[4];
    const float* W2    = (const float*)d_in[5];
    const float* b2    = (const float*)d_in[6];
    const float* g2    = (const float*)d_in[7];
    const float* be2   = (const float*)d_in[8];
    const int* senders   = (const int*)d_in[9];
    const int* receivers = (const int*)d_in[10];

    const int N = in_sizes[0] / D;
    const int E = in_sizes[9];
    float* out = (float*)d_out;

    char* ws = (char*)d_ws;
    unsigned short* qb = (unsigned short*)ws; ws += (size_t)N * D * 2;
    unsigned short* wt = (unsigned short*)ws; ws += 4 * 128 * 128 * 2;
    int* cnt      = (int*)ws;    ws += (size_t)N * 4;
    int* rowptr   = (int*)ws;    ws += (size_t)(N + 2) * 4;
    int* cursor   = (int*)ws;    ws += (size_t)N * 4;
    int* bsum     = (int*)ws;    ws += 256 * 4;
    int* ssend    = (int*)ws;    ws += (size_t)E * 4;

    zero_cnt_kernel<<<(N / 4 + 255) / 256, 256, 0, stream>>>(cnt, N);

    // weight split (fragment-ordered hi/lo), then column-split-pair MFMA MLP
    wsplit_kernel<<<16, 256, 0, stream>>>(W1, W2, wt);
    const int nwt = (N + 15) / 16;
    mlp_pair_kernel<<<(nwt + 1) / 2, 256, 0, stream>>>(
        nodes, wt, b1, g1, be1, b2, g2, be2, qb, N);

    // CSR build (receiver-sorted sender list)
    const int nb = (N + 1023) / 1024;
    hist_kernel<<<(E + 255) / 256, 256, 0, stream>>>(receivers, cnt, E);
    scan_blocks_kernel<<<nb, 256, 0, stream>>>(cnt, rowptr, bsum, N);
    scan_top_kernel<<<1, 256, 0, stream>>>(bsum, nb);
    scan_add_kernel<<<(N + 255) / 256, 256, 0, stream>>>(rowptr, cursor, bsum, N, E);
    fill_kernel<<<(E + 255) / 256, 256, 0, stream>>>(senders, receivers, cursor, ssend, E);

    // fused attention + epilogue
    node_attn_kernel<<<(N + 3) / 4, 256, 0, stream>>>(qb, rowptr, ssend, out, N);
}

// Round 8
// 135.412 us; speedup vs baseline: 1.1630x; 1.0090x over previous
//
#include <hip/hip_runtime.h>

constexpr int D  = 128;   // feature dim (= H*F)
constexpr int NH = 4;     // heads
constexpr int NF = 32;    // features per head

typedef __attribute__((ext_vector_type(8))) short bfrag;   // 8 bf16 = 4 VGPR
typedef __attribute__((ext_vector_type(4))) float ffrag;   // 4 f32 acc

// bf16 RNE helpers
__device__ __forceinline__ unsigned short bf16h(float x) {
    unsigned u = __float_as_uint(x);
    u += 0x7fffu + ((u >> 16) & 1u);
    return (unsigned short)(u >> 16);
}
__device__ __forceinline__ float bf16tof(unsigned short h) {
    return __uint_as_float(((unsigned)h) << 16);
}

// ---- zero the histogram counters ----
__global__ __launch_bounds__(256) void zero_cnt_kernel(int* __restrict__ p, int n)
{
    const int i4 = (blockIdx.x * blockDim.x + threadIdx.x) * 4;
    if (i4 + 3 < n) {
        *(int4*)&p[i4] = {0, 0, 0, 0};
    } else if (i4 < n) {
        for (int i = i4; i < n; ++i) p[i] = 0;
    }
}

// ---- one-time: split W1,W2 into bf16 hi/lo planes, FRAGMENT-ORDERED ----
// 1KB chunks indexed ((L*2+plane)*32 + ctg*4 + ks); chunk[lane][i] =
// plane(W[ks*32 + (lane>>4)*8 + i][ctg*16 + (lane&15)]). A B-frag load is one
// coalesced global_load_dwordx4 at chunkbase + lane*16B.
__global__ __launch_bounds__(256) void wsplit_kernel(
    const float* __restrict__ W1, const float* __restrict__ W2,
    unsigned short* __restrict__ wt)
{
    const int L  = blockIdx.x >> 3;          // 16 blocks: L in {0,1}, ctg in 0..7
    const int ct = blockIdx.x & 7;
    const float* W = L ? W2 : W1;
    const int ks   = threadIdx.x >> 6;
    const int lane = threadIdx.x & 63;
    const int lg = lane >> 4, lc = lane & 15;
    unsigned short* Hp = wt + ((size_t)(L * 2 + 0) * 32 + ct * 4 + ks) * 512 + lane * 8;
    unsigned short* Lp = wt + ((size_t)(L * 2 + 1) * 32 + ct * 4 + ks) * 512 + lane * 8;
    #pragma unroll
    for (int i = 0; i < 8; ++i) {
        const int k = ks * 32 + lg * 8 + i;
        const int c = ct * 16 + lc;
        const float v = W[(size_t)k * 128 + c];
        const unsigned short hh = bf16h(v);
        Hp[i] = hh;
        Lp[i] = bf16h(v - bf16tof(hh));
    }
}

// ---- MFMA MLP, column-split pairs, high-ILP ----
// R7 post-mortem: under (256,4) the allocator built a 60-VGPR serial kernel
// (load-batch -> wait -> dependent MFMA chain per ct) — exposed L2 latency
// every ct, same ~45us for every structure. Fix: (256,2) (cap 256 VGPR) and
// ct-PAIR processing: 16 B-frags (64 VGPR) loaded up front, then 4 independent
// MFMA chains (2ct x accH/accX) interleaved. Live set ~135 regs, no spill.
__global__ __launch_bounds__(256, 2) void mlp_pair_kernel(
    const float* __restrict__ X,
    const unsigned short* __restrict__ WF,
    const float* __restrict__ b1, const float* __restrict__ g1, const float* __restrict__ be1,
    const float* __restrict__ b2, const float* __restrict__ g2, const float* __restrict__ be2,
    unsigned short* __restrict__ Q, int N)
{
    constexpr int PW = 132;                    // u32 pitch
    __shared__ unsigned Scr[2][16 * PW];       // per-pair packed h1 (hi|lo u32)
    __shared__ float Sums[2][2][16][2];        // [pair][wavehalf][row][s,ss]

    const int tid  = threadIdx.x;
    const int lane = tid & 63;
    const int wave = tid >> 6;
    const int pair = wave >> 1;
    const int w    = wave & 1;                 // column half: cols w*64..w*64+63
    const int lc   = lane & 15;
    const int lg   = lane >> 4;

    const int nwt = (N + 15) >> 4;
    const int tileIdx = blockIdx.x * 2 + pair;
    const bool valid = tileIdx < nwt;
    const int n0w = (valid ? tileIdx : (nwt - 1)) * 16;

    // ---- LN params for this wave's 4 col-tiles (ctg = w*4+ct) ----
    float b1v[4], g1v[4], t1v[4], b2v[4], g2v[4], t2v[4];
    #pragma unroll
    for (int ct = 0; ct < 4; ++ct) {
        const int col = (w * 4 + ct) * 16 + lc;
        b1v[ct] = b1[col]; g1v[ct] = g1[col]; t1v[ct] = be1[col];
        b2v[ct] = b2[col]; g2v[ct] = g2[col]; t2v[ct] = be2[col];
    }

    // ---- A-frags layer 1: from global X, split in-reg ----
    bfrag ah[4], al[4];
    {
        const int rowx = (n0w + lc < N) ? (n0w + lc) : (N - 1);
        const float* xr = X + (size_t)rowx * 128 + lg * 8;
        #pragma unroll
        for (int ks = 0; ks < 4; ++ks) {
            const float4 a = *(const float4*)&xr[ks * 32];
            const float4 b = *(const float4*)&xr[ks * 32 + 4];
            const float f[8] = {a.x, a.y, a.z, a.w, b.x, b.y, b.z, b.w};
            #pragma unroll
            for (int i = 0; i < 8; ++i) {
                const unsigned short hh = bf16h(f[i]);
                ah[ks][i] = (short)hh;
                al[ks][i] = (short)bf16h(f[i] - bf16tof(hh));
            }
        }
    }

    ffrag accH[4], accX[4];

    // ---- high-ILP gemm for one layer: process ct in pairs ----
    auto gemmLayer = [&](int hiBase, int loBase) {
        #pragma unroll
        for (int cp = 0; cp < 2; ++cp) {
            const int ct0 = cp * 2, ct1 = cp * 2 + 1;
            const int cg0 = w * 4 + ct0, cg1 = w * 4 + ct1;
            const unsigned short* bh0p = WF + (size_t)(hiBase + cg0 * 4) * 512 + lane * 8;
            const unsigned short* bl0p = WF + (size_t)(loBase + cg0 * 4) * 512 + lane * 8;
            const unsigned short* bh1p = WF + (size_t)(hiBase + cg1 * 4) * 512 + lane * 8;
            const unsigned short* bl1p = WF + (size_t)(loBase + cg1 * 4) * 512 + lane * 8;
            // load ALL 16 B-frags for the pair up front (64 VGPRs, visible ILP)
            bfrag bh0[4], bl0[4], bh1[4], bl1[4];
            #pragma unroll
            for (int ks = 0; ks < 4; ++ks) {
                bh0[ks] = *(const bfrag*)(bh0p + ks * 512);
                bl0[ks] = *(const bfrag*)(bl0p + ks * 512);
                bh1[ks] = *(const bfrag*)(bh1p + ks * 512);
                bl1[ks] = *(const bfrag*)(bl1p + ks * 512);
            }
            ffrag aH0 = (ffrag){0.f, 0.f, 0.f, 0.f};
            ffrag aX0 = (ffrag){0.f, 0.f, 0.f, 0.f};
            ffrag aH1 = (ffrag){0.f, 0.f, 0.f, 0.f};
            ffrag aX1 = (ffrag){0.f, 0.f, 0.f, 0.f};
            // 4 independent chains, interleaved by the scheduler
            #pragma unroll
            for (int ks = 0; ks < 4; ++ks) {
                aH0 = __builtin_amdgcn_mfma_f32_16x16x32_bf16(ah[ks], bh0[ks], aH0, 0, 0, 0);
                aH1 = __builtin_amdgcn_mfma_f32_16x16x32_bf16(ah[ks], bh1[ks], aH1, 0, 0, 0);
                aX0 = __builtin_amdgcn_mfma_f32_16x16x32_bf16(ah[ks], bl0[ks], aX0, 0, 0, 0);
                aX1 = __builtin_amdgcn_mfma_f32_16x16x32_bf16(ah[ks], bl1[ks], aX1, 0, 0, 0);
                aX0 = __builtin_amdgcn_mfma_f32_16x16x32_bf16(al[ks], bh0[ks], aX0, 0, 0, 0);
                aX1 = __builtin_amdgcn_mfma_f32_16x16x32_bf16(al[ks], bh1[ks], aX1, 0, 0, 0);
            }
            accH[ct0] = aH0; accX[ct0] = aX0;
            accH[ct1] = aH1; accX[ct1] = aX1;
        }
    };

    // ================= layer 1 =================
    gemmLayer(0, 32);

    // ---- LN1 partial sums (this wave's 64 cols) ----
    float tv[4][4];                            // [j][ct]
    #pragma unroll
    for (int j = 0; j < 4; ++j) {
        float s = 0.f, ss = 0.f;
        #pragma unroll
        for (int ct = 0; ct < 4; ++ct) {
            const float t = accH[ct][j] + accX[ct][j] + b1v[ct];
            tv[j][ct] = t;
            s += t; ss += t * t;
        }
        #pragma unroll
        for (int off = 1; off <= 8; off <<= 1) {
            s  += __shfl_xor(s,  off, 16);
            ss += __shfl_xor(ss, off, 16);
        }
        if (lc == 0) {
            Sums[pair][w][lg * 4 + j][0] = s;
            Sums[pair][w][lg * 4 + j][1] = ss;
        }
    }
    __syncthreads();                           // partials visible to partner

    // ---- LN1 finalize + pack h1 into pair scratch ----
    #pragma unroll
    for (int j = 0; j < 4; ++j) {
        const int row = lg * 4 + j;
        const float s  = Sums[pair][0][row][0] + Sums[pair][1][row][0];
        const float ss = Sums[pair][0][row][1] + Sums[pair][1][row][1];
        const float mu   = s * (1.f / 128.f);
        const float var  = fmaxf(ss * (1.f / 128.f) - mu * mu, 0.f);
        const float rstd = rsqrtf(var + 1e-6f);
        #pragma unroll
        for (int ct = 0; ct < 4; ++ct) {
            const float o = fmaxf((tv[j][ct] - mu) * rstd * g1v[ct] + t1v[ct], 0.f);
            const unsigned short hh = bf16h(o);
            const unsigned short ll = bf16h(o - bf16tof(hh));
            Scr[pair][row * PW + (w * 4 + ct) * 16 + lc] =
                (unsigned)hh | ((unsigned)ll << 16);
        }
    }
    __syncthreads();                           // full h1 tile visible

    // ---- A-frags layer 2: full K from pair scratch ----
    #pragma unroll
    for (int ks = 0; ks < 4; ++ks) {
        const uint4 r0 = *(const uint4*)&Scr[pair][lc * PW + ks * 32 + lg * 8];
        const uint4 r1 = *(const uint4*)&Scr[pair][lc * PW + ks * 32 + lg * 8 + 4];
        const unsigned rr[8] = {r0.x, r0.y, r0.z, r0.w, r1.x, r1.y, r1.z, r1.w};
        #pragma unroll
        for (int i = 0; i < 8; ++i) {
            ah[ks][i] = (short)(rr[i] & 0xffffu);
            al[ks][i] = (short)(rr[i] >> 16);
        }
    }

    // ================= layer 2 =================
    gemmLayer(64, 96);

    // ---- LN2 partial sums ----
    #pragma unroll
    for (int j = 0; j < 4; ++j) {
        float s = 0.f, ss = 0.f;
        #pragma unroll
        for (int ct = 0; ct < 4; ++ct) {
            const float t = accH[ct][j] + accX[ct][j] + b2v[ct];
            tv[j][ct] = t;
            s += t; ss += t * t;
        }
        #pragma unroll
        for (int off = 1; off <= 8; off <<= 1) {
            s  += __shfl_xor(s,  off, 16);
            ss += __shfl_xor(ss, off, 16);
        }
        if (lc == 0) {
            Sums[pair][w][lg * 4 + j][0] = s;
            Sums[pair][w][lg * 4 + j][1] = ss;
        }
    }
    __syncthreads();                           // LN2 partials visible

    // ---- LN2 finalize + store bf16 q ----
    #pragma unroll
    for (int j = 0; j < 4; ++j) {
        const int row = lg * 4 + j;
        const float s  = Sums[pair][0][row][0] + Sums[pair][1][row][0];
        const float ss = Sums[pair][0][row][1] + Sums[pair][1][row][1];
        const float mu   = s * (1.f / 128.f);
        const float var  = fmaxf(ss * (1.f / 128.f) - mu * mu, 0.f);
        const float rstd = rsqrtf(var + 1e-6f);
        const int grow = n0w + row;
        if (valid && grow < N) {
            #pragma unroll
            for (int ct = 0; ct < 4; ++ct) {
                const float o = fmaxf((tv[j][ct] - mu) * rstd * g2v[ct] + t2v[ct], 0.f);
                Q[(size_t)grow * 128 + (w * 4 + ct) * 16 + lc] = bf16h(o);
            }
        }
    }
}

// ---- CSR build: histogram ----
__global__ __launch_bounds__(256) void hist_kernel(
    const int* __restrict__ recv, int* __restrict__ cnt, int E)
{
    int i = blockIdx.x * blockDim.x + threadIdx.x;
    if (i < E) atomicAdd(&cnt[recv[i]], 1);
}

// ---- CSR build: per-1024-chunk exclusive scan ----
__global__ __launch_bounds__(256) void scan_blocks_kernel(
    const int* __restrict__ cnt, int* __restrict__ rowptr,
    int* __restrict__ bsum, int N)
{
    __shared__ int lds[256];
    const int tid = threadIdx.x;
    const int base = blockIdx.x * 1024 + tid * 4;
    int v0 = (base + 0 < N) ? cnt[base + 0] : 0;
    int v1 = (base + 1 < N) ? cnt[base + 1] : 0;
    int v2 = (base + 2 < N) ? cnt[base + 2] : 0;
    int v3 = (base + 3 < N) ? cnt[base + 3] : 0;
    const int tsum = v0 + v1 + v2 + v3;
    lds[tid] = tsum;
    __syncthreads();
    for (int off = 1; off < 256; off <<= 1) {
        int t = (tid >= off) ? lds[tid - off] : 0;
        __syncthreads();
        lds[tid] += t;
        __syncthreads();
    }
    int run = lds[tid] - tsum;
    if (base + 0 < N) rowptr[base + 0] = run;
    run += v0;
    if (base + 1 < N) rowptr[base + 1] = run;
    run += v1;
    if (base + 2 < N) rowptr[base + 2] = run;
    run += v2;
    if (base + 3 < N) rowptr[base + 3] = run;
    if (tid == 255) bsum[blockIdx.x] = lds[255];
}

// ---- CSR build: scan block sums ----
__global__ __launch_bounds__(256) void scan_top_kernel(int* bsum, int nb)
{
    __shared__ int lds[256];
    const int tid = threadIdx.x;
    int v = (tid < nb) ? bsum[tid] : 0;
    lds[tid] = v;
    __syncthreads();
    for (int off = 1; off < 256; off <<= 1) {
        int t = (tid >= off) ? lds[tid - off] : 0;
        __syncthreads();
        lds[tid] += t;
        __syncthreads();
    }
    if (tid < nb) bsum[tid] = lds[tid] - v;
}

// ---- CSR build: add chunk offsets ----
__global__ __launch_bounds__(256) void scan_add_kernel(
    int* __restrict__ rowptr, int* __restrict__ cursor,
    const int* __restrict__ bsum, int N, int E)
{
    int i = blockIdx.x * blockDim.x + threadIdx.x;
    if (i < N) {
        int v = rowptr[i] + bsum[i >> 10];
        rowptr[i] = v;
        cursor[i] = v;
    }
    if (i == 0) rowptr[N] = E;
}

// ---- CSR build: bucket-fill sorted sender ids ----
__global__ __launch_bounds__(256) void fill_kernel(
    const int* __restrict__ senders, const int* __restrict__ receivers,
    int* __restrict__ cursor, int* __restrict__ ssend, int E)
{
    int e = blockIdx.x * blockDim.x + threadIdx.x;
    if (e < E) {
        int r = receivers[e];
        int pos = atomicAdd(&cursor[r], 1);
        ssend[pos] = senders[e];
    }
}

// ---- fused per-node attention (bf16 q) ----
__global__ __launch_bounds__(256) void node_attn_kernel(
    const unsigned short* __restrict__ q, const int* __restrict__ rowptr,
    const int* __restrict__ ssend, float* __restrict__ out, int N)
{
    const int lane = threadIdx.x & 63;
    const int hl   = lane & 31;
    const int half = lane >> 5;
    const int wid  = (blockIdx.x * blockDim.x + threadIdx.x) >> 6;
    const int nw   = (gridDim.x * blockDim.x) >> 6;

    for (int n = wid; n < N; n += nw) {
        const uint2 braw = *(const uint2*)&q[(size_t)n * D + hl * 4];
        const float b0 = __uint_as_float(braw.x << 16);
        const float b1 = __uint_as_float(braw.x & 0xffff0000u);
        const float b2 = __uint_as_float(braw.y << 16);
        const float b3 = __uint_as_float(braw.y & 0xffff0000u);

        const int beg = rowptr[n], end = rowptr[n + 1];
        float m = -1e30f, l = 0.f;
        float c0 = 0.f, c1 = 0.f, c2 = 0.f, c3 = 0.f;

        int j = beg + half;
        uint2 raw = {0u, 0u};
        if (j < end)
            raw = *(const uint2*)&q[(size_t)ssend[j] * D + hl * 4];
        for (; j < end; j += 2) {
            const uint2 cur = raw;
            if (j + 2 < end)
                raw = *(const uint2*)&q[(size_t)ssend[j + 2] * D + hl * 4];
            const float a0 = __uint_as_float(cur.x << 16);
            const float a1 = __uint_as_float(cur.x & 0xffff0000u);
            const float a2 = __uint_as_float(cur.y << 16);
            const float a3 = __uint_as_float(cur.y & 0xffff0000u);
            float p = a0 * b0 + a1 * b1 + a2 * b2 + a3 * b3;
            p += __shfl_xor(p, 1);
            p += __shfl_xor(p, 2);
            p += __shfl_xor(p, 4);
            const float logit = p * 0.17677669529663687f;   // 1/sqrt(32)
            const float nm = fmaxf(m, logit);
            const float sc = __expf(m - nm);
            const float u  = __expf(logit - nm);
            l  = l * sc + u;
            c0 = c0 * sc + u * a0;
            c1 = c1 * sc + u * a1;
            c2 = c2 * sc + u * a2;
            c3 = c3 * sc + u * a3;
            m = nm;
        }

        const float om  = __shfl_xor(m, 32);
        const float ol  = __shfl_xor(l, 32);
        const float oc0 = __shfl_xor(c0, 32);
        const float oc1 = __shfl_xor(c1, 32);
        const float oc2 = __shfl_xor(c2, 32);
        const float oc3 = __shfl_xor(c3, 32);
        const float nm = fmaxf(m, om);
        const float s0 = __expf(m - nm), s1 = __expf(om - nm);
        const float lt = l * s0 + ol * s1;
        const float inv = (lt > 0.f) ? (1.f / lt) : 0.f;
        float r0 = fmaxf((c0 * s0 + oc0 * s1) * inv, 0.f);
        float r1 = fmaxf((c1 * s0 + oc1 * s1) * inv, 0.f);
        float r2 = fmaxf((c2 * s0 + oc2 * s1) * inv, 0.f);
        float r3 = fmaxf((c3 * s0 + oc3 * s1) * inv, 0.f);

        r0 += __shfl_xor(r0, 8);  r0 += __shfl_xor(r0, 16);
        r1 += __shfl_xor(r1, 8);  r1 += __shfl_xor(r1, 16);
        r2 += __shfl_xor(r2, 8);  r2 += __shfl_xor(r2, 16);
        r3 += __shfl_xor(r3, 8);  r3 += __shfl_xor(r3, 16);
        if (lane < 8) {
            float4 o = {0.25f * r0, 0.25f * r1, 0.25f * r2, 0.25f * r3};
            *(float4*)&out[(size_t)n * NF + lane * 4] = o;
        }
    }
}

extern "C" void kernel_launch(void* const* d_in, const int* in_sizes, int n_in,
                              void* d_out, int out_size, void* d_ws, size_t ws_size,
                              hipStream_t stream)
{
    const float* nodes = (const float*)d_in[0];
    const float* W1    = (const float*)d_in[1];
    const float* b1    = (const float*)d_in[2];
    const float* g1    = (const float*)d_in[3];
    const float* be1   = (const float*)d_in[4];
    const float* W2    = (const float*)d_in[5];
    const float* b2    = (const float*)d_in[6];
    const float* g2    = (const float*)d_in[7];
    const float* be2   = (const float*)d_in[8];
    const int* senders   = (const int*)d_in[9];
    const int* receivers = (const int*)d_in[10];

    const int N = in_sizes[0] / D;
    const int E = in_sizes[9];
    float* out = (float*)d_out;

    char* ws = (char*)d_ws;
    unsigned short* qb = (unsigned short*)ws; ws += (size_t)N * D * 2;
    unsigned short* wt = (unsigned short*)ws; ws += 4 * 128 * 128 * 2;
    int* cnt      = (int*)ws;    ws += (size_t)N * 4;
    int* rowptr   = (int*)ws;    ws += (size_t)(N + 2) * 4;
    int* cursor   = (int*)ws;    ws += (size_t)N * 4;
    int* bsum     = (int*)ws;    ws += 256 * 4;
    int* ssend    = (int*)ws;    ws += (size_t)E * 4;

    zero_cnt_kernel<<<(N / 4 + 255) / 256, 256, 0, stream>>>(cnt, N);

    // weight split (fragment-ordered hi/lo), then high-ILP pair MFMA MLP
    wsplit_kernel<<<16, 256, 0, stream>>>(W1, W2, wt);
    const int nwt = (N + 15) / 16;
    mlp_pair_kernel<<<(nwt + 1) / 2, 256, 0, stream>>>(
        nodes, wt, b1, g1, be1, b2, g2, be2, qb, N);

    // CSR build (receiver-sorted sender list)
    const int nb = (N + 1023) / 1024;
    hist_kernel<<<(E + 255) / 256, 256, 0, stream>>>(receivers, cnt, E);
    scan_blocks_kernel<<<nb, 256, 0, stream>>>(cnt, rowptr, bsum, N);
    scan_top_kernel<<<1, 256, 0, stream>>>(bsum, nb);
    scan_add_kernel<<<(N + 255) / 256, 256, 0, stream>>>(rowptr, cursor, bsum, N, E);
    fill_kernel<<<(E + 255) / 256, 256, 0, stream>>>(senders, receivers, cursor, ssend, E);

    // fused attention + epilogue
    node_attn_kernel<<<(N + 3) / 4, 256, 0, stream>>>(qb, rowptr, ssend, out, N);
}

// Round 9
// 133.124 us; speedup vs baseline: 1.1830x; 1.0172x over previous
//
#include <hip/hip_runtime.h>

constexpr int D  = 128;   // feature dim (= H*F)
constexpr int NH = 4;     // heads
constexpr int NF = 32;    // features per head

typedef __attribute__((ext_vector_type(8))) short bfrag;   // 8 bf16 = 4 VGPR
typedef __attribute__((ext_vector_type(4))) float ffrag;   // 4 f32 acc

// bf16 RNE helpers
__device__ __forceinline__ unsigned short bf16h(float x) {
    unsigned u = __float_as_uint(x);
    u += 0x7fffu + ((u >> 16) & 1u);
    return (unsigned short)(u >> 16);
}
__device__ __forceinline__ float bf16tof(unsigned short h) {
    return __uint_as_float(((unsigned)h) << 16);
}

// ---- zero the histogram counters ----
__global__ __launch_bounds__(256) void zero_cnt_kernel(int* __restrict__ p, int n)
{
    const int i4 = (blockIdx.x * blockDim.x + threadIdx.x) * 4;
    if (i4 + 3 < n) {
        *(int4*)&p[i4] = {0, 0, 0, 0};
    } else if (i4 < n) {
        for (int i = i4; i < n; ++i) p[i] = 0;
    }
}

// ---- one-time: split W1,W2 into bf16 hi/lo planes, FRAGMENT-ORDERED ----
// 1KB chunks indexed ((L*2+plane)*32 + ctg*4 + ks); chunk[lane][i] =
// plane(W[ks*32 + (lane>>4)*8 + i][ctg*16 + (lane&15)]). A B-frag load is one
// coalesced global_load_dwordx4 at chunkbase + lane*16B.
__global__ __launch_bounds__(256) void wsplit_kernel(
    const float* __restrict__ W1, const float* __restrict__ W2,
    unsigned short* __restrict__ wt)
{
    const int L  = blockIdx.x >> 3;          // 16 blocks: L in {0,1}, ctg in 0..7
    const int ct = blockIdx.x & 7;
    const float* W = L ? W2 : W1;
    const int ks   = threadIdx.x >> 6;
    const int lane = threadIdx.x & 63;
    const int lg = lane >> 4, lc = lane & 15;
    unsigned short* Hp = wt + ((size_t)(L * 2 + 0) * 32 + ct * 4 + ks) * 512 + lane * 8;
    unsigned short* Lp = wt + ((size_t)(L * 2 + 1) * 32 + ct * 4 + ks) * 512 + lane * 8;
    #pragma unroll
    for (int i = 0; i < 8; ++i) {
        const int k = ks * 32 + lg * 8 + i;
        const int c = ct * 16 + lc;
        const float v = W[(size_t)k * 128 + c];
        const unsigned short hh = bf16h(v);
        Hp[i] = hh;
        Lp[i] = bf16h(v - bf16tof(hh));
    }
}

// ---- MFMA MLP, software-pipelined B-prefetch ----
// R8 post-mortem: every source structure compiled to the same 64-VGPR serial
// load->wait->MFMA shape (allocator sinks loads to uses), exposing ~300cy L2
// latency x 16 batches/wave. Fix: double-buffered ct pipeline where each
// prefetch's consumer is one compute phase later, pinned with
// sched_barrier(0) so loads cannot sink past it. WAR (compute B0 then reload
// B0) + fence force both buffers live -> compiler must keep ~150 VGPRs and
// the load flies under the other buffer's 12-MFMA phase.
__global__ __launch_bounds__(256, 2) void mlp_pipe_kernel(
    const float* __restrict__ X,
    const unsigned short* __restrict__ WF,
    const float* __restrict__ b1, const float* __restrict__ g1, const float* __restrict__ be1,
    const float* __restrict__ b2, const float* __restrict__ g2, const float* __restrict__ be2,
    unsigned short* __restrict__ Q, int N)
{
    constexpr int PW = 132;                    // u32 pitch (528B, b128-aligned)
    __shared__ unsigned HL[4 * 16 * PW];       // 33792 B per block

    const int tid  = threadIdx.x;
    const int lane = tid & 63;
    const int wave = tid >> 6;
    const int lc   = lane & 15;
    const int lg   = lane >> 4;
    const int n0w  = (blockIdx.x * 4 + wave) * 16;
    if (n0w >= N) return;
    unsigned* hl = &HL[wave * 16 * PW];

    bfrag ah[4], al[4];

    // ---- A-frags layer 1: direct from global X, split in-reg ----
    {
        const int rowx = (n0w + lc < N) ? (n0w + lc) : (N - 1);
        const float* xr = X + (size_t)rowx * 128 + lg * 8;
        #pragma unroll
        for (int ks = 0; ks < 4; ++ks) {
            const float4 a = *(const float4*)&xr[ks * 32];
            const float4 b = *(const float4*)&xr[ks * 32 + 4];
            const float f[8] = {a.x, a.y, a.z, a.w, b.x, b.y, b.z, b.w};
            #pragma unroll
            for (int i = 0; i < 8; ++i) {
                const unsigned short hh = bf16h(f[i]);
                ah[ks][i] = (short)hh;
                al[ks][i] = (short)bf16h(f[i] - bf16tof(hh));
            }
        }
    }

    bfrag Bh0[4], Bl0[4], Bh1[4], Bl1[4];      // two B buffers (32 VGPR each)
    ffrag accF[8];

#define LOADB(BH, BL, hiBase, loBase, ctg)                                     \
    {                                                                          \
        const unsigned short* hp_ = WF + (size_t)((hiBase) + (ctg) * 4) * 512 + lane * 8; \
        const unsigned short* lp_ = WF + (size_t)((loBase) + (ctg) * 4) * 512 + lane * 8; \
        _Pragma("unroll")                                                      \
        for (int ks_ = 0; ks_ < 4; ++ks_) {                                    \
            BH[ks_] = *(const bfrag*)(hp_ + ks_ * 512);                        \
            BL[ks_] = *(const bfrag*)(lp_ + ks_ * 512);                        \
        }                                                                      \
    }

#define COMPB(BH, BL, dst)                                                     \
    {                                                                          \
        ffrag aH_ = (ffrag){0.f, 0.f, 0.f, 0.f};                               \
        ffrag aX_ = (ffrag){0.f, 0.f, 0.f, 0.f};                               \
        _Pragma("unroll")                                                      \
        for (int ks_ = 0; ks_ < 4; ++ks_) {                                    \
            aH_ = __builtin_amdgcn_mfma_f32_16x16x32_bf16(ah[ks_], BH[ks_], aH_, 0, 0, 0); \
            aX_ = __builtin_amdgcn_mfma_f32_16x16x32_bf16(ah[ks_], BL[ks_], aX_, 0, 0, 0); \
            aX_ = __builtin_amdgcn_mfma_f32_16x16x32_bf16(al[ks_], BH[ks_], aX_, 0, 0, 0); \
        }                                                                      \
        dst = aH_ + aX_;                                                       \
    }

#define GEMM_LAYER(hiBase, loBase)                                             \
    LOADB(Bh0, Bl0, hiBase, loBase, 0)                                         \
    LOADB(Bh1, Bl1, hiBase, loBase, 1)                                         \
    __builtin_amdgcn_sched_barrier(0);                                         \
    COMPB(Bh0, Bl0, accF[0])                                                   \
    LOADB(Bh0, Bl0, hiBase, loBase, 2)                                         \
    __builtin_amdgcn_sched_barrier(0);                                         \
    COMPB(Bh1, Bl1, accF[1])                                                   \
    LOADB(Bh1, Bl1, hiBase, loBase, 3)                                         \
    __builtin_amdgcn_sched_barrier(0);                                         \
    COMPB(Bh0, Bl0, accF[2])                                                   \
    LOADB(Bh0, Bl0, hiBase, loBase, 4)                                         \
    __builtin_amdgcn_sched_barrier(0);                                         \
    COMPB(Bh1, Bl1, accF[3])                                                   \
    LOADB(Bh1, Bl1, hiBase, loBase, 5)                                         \
    __builtin_amdgcn_sched_barrier(0);                                         \
    COMPB(Bh0, Bl0, accF[4])                                                   \
    LOADB(Bh0, Bl0, hiBase, loBase, 6)                                         \
    __builtin_amdgcn_sched_barrier(0);                                         \
    COMPB(Bh1, Bl1, accF[5])                                                   \
    LOADB(Bh1, Bl1, hiBase, loBase, 7)                                         \
    __builtin_amdgcn_sched_barrier(0);                                         \
    COMPB(Bh0, Bl0, accF[6])                                                   \
    COMPB(Bh1, Bl1, accF[7])

    // ================= layer 1 =================
    GEMM_LAYER(0, 32)

    // ---- LN1 + ReLU -> packed hi|lo u32 into per-wave LDS ([row][col=k]) ----
    {
        float bb[8], gg[8], tt[8];
        #pragma unroll
        for (int ct = 0; ct < 8; ++ct) {
            const int col = ct * 16 + lc;
            bb[ct] = b1[col]; gg[ct] = g1[col]; tt[ct] = be1[col];
        }
        #pragma unroll
        for (int j = 0; j < 4; ++j) {
            float t[8], s = 0.f, ss = 0.f;
            #pragma unroll
            for (int ct = 0; ct < 8; ++ct) {
                t[ct] = accF[ct][j] + bb[ct];
                s += t[ct]; ss += t[ct] * t[ct];
            }
            #pragma unroll
            for (int off = 1; off <= 8; off <<= 1) {
                s  += __shfl_xor(s,  off, 16);
                ss += __shfl_xor(ss, off, 16);
            }
            const float mu   = s * (1.f / 128.f);
            const float var  = fmaxf(ss * (1.f / 128.f) - mu * mu, 0.f);
            const float rstd = rsqrtf(var + 1e-6f);
            const int row = lg * 4 + j;
            #pragma unroll
            for (int ct = 0; ct < 8; ++ct) {
                const float o = fmaxf((t[ct] - mu) * rstd * gg[ct] + tt[ct], 0.f);
                const unsigned short hh = bf16h(o);
                const unsigned short ll = bf16h(o - bf16tof(hh));
                hl[row * PW + ct * 16 + lc] = (unsigned)hh | ((unsigned)ll << 16);
            }
        }
    }

    // wave-local fence: all 64 lanes' LDS writes complete before cross-lane reads
    asm volatile("s_waitcnt lgkmcnt(0)" ::: "memory");

    // ---- A-frags layer 2: from packed LDS (row = lc, k = ks*32+lg*8+i) ----
    #pragma unroll
    for (int ks = 0; ks < 4; ++ks) {
        const uint4 r0 = *(const uint4*)&hl[lc * PW + ks * 32 + lg * 8];
        const uint4 r1 = *(const uint4*)&hl[lc * PW + ks * 32 + lg * 8 + 4];
        const unsigned rr[8] = {r0.x, r0.y, r0.z, r0.w, r1.x, r1.y, r1.z, r1.w};
        #pragma unroll
        for (int i = 0; i < 8; ++i) {
            ah[ks][i] = (short)(rr[i] & 0xffffu);
            al[ks][i] = (short)(rr[i] >> 16);
        }
    }

    // ================= layer 2 =================
    GEMM_LAYER(64, 96)

#undef GEMM_LAYER
#undef COMPB
#undef LOADB

    // ---- LN2 + ReLU -> bf16 q (global) ----
    {
        float bb[8], gg[8], tt[8];
        #pragma unroll
        for (int ct = 0; ct < 8; ++ct) {
            const int col = ct * 16 + lc;
            bb[ct] = b2[col]; gg[ct] = g2[col]; tt[ct] = be2[col];
        }
        #pragma unroll
        for (int j = 0; j < 4; ++j) {
            float t[8], s = 0.f, ss = 0.f;
            #pragma unroll
            for (int ct = 0; ct < 8; ++ct) {
                t[ct] = accF[ct][j] + bb[ct];
                s += t[ct]; ss += t[ct] * t[ct];
            }
            #pragma unroll
            for (int off = 1; off <= 8; off <<= 1) {
                s  += __shfl_xor(s,  off, 16);
                ss += __shfl_xor(ss, off, 16);
            }
            const float mu   = s * (1.f / 128.f);
            const float var  = fmaxf(ss * (1.f / 128.f) - mu * mu, 0.f);
            const float rstd = rsqrtf(var + 1e-6f);
            const int grow = n0w + lg * 4 + j;
            if (grow < N) {
                #pragma unroll
                for (int ct = 0; ct < 8; ++ct) {
                    const float o = fmaxf((t[ct] - mu) * rstd * gg[ct] + tt[ct], 0.f);
                    Q[(size_t)grow * 128 + ct * 16 + lc] = bf16h(o);
                }
            }
        }
    }
}

// ---- CSR build: histogram ----
__global__ __launch_bounds__(256) void hist_kernel(
    const int* __restrict__ recv, int* __restrict__ cnt, int E)
{
    int i = blockIdx.x * blockDim.x + threadIdx.x;
    if (i < E) atomicAdd(&cnt[recv[i]], 1);
}

// ---- CSR build: per-1024-chunk exclusive scan ----
__global__ __launch_bounds__(256) void scan_blocks_kernel(
    const int* __restrict__ cnt, int* __restrict__ rowptr,
    int* __restrict__ bsum, int N)
{
    __shared__ int lds[256];
    const int tid = threadIdx.x;
    const int base = blockIdx.x * 1024 + tid * 4;
    int v0 = (base + 0 < N) ? cnt[base + 0] : 0;
    int v1 = (base + 1 < N) ? cnt[base + 1] : 0;
    int v2 = (base + 2 < N) ? cnt[base + 2] : 0;
    int v3 = (base + 3 < N) ? cnt[base + 3] : 0;
    const int tsum = v0 + v1 + v2 + v3;
    lds[tid] = tsum;
    __syncthreads();
    for (int off = 1; off < 256; off <<= 1) {
        int t = (tid >= off) ? lds[tid - off] : 0;
        __syncthreads();
        lds[tid] += t;
        __syncthreads();
    }
    int run = lds[tid] - tsum;
    if (base + 0 < N) rowptr[base + 0] = run;
    run += v0;
    if (base + 1 < N) rowptr[base + 1] = run;
    run += v1;
    if (base + 2 < N) rowptr[base + 2] = run;
    run += v2;
    if (base + 3 < N) rowptr[base + 3] = run;
    if (tid == 255) bsum[blockIdx.x] = lds[255];
}

// ---- CSR build: scan block sums ----
__global__ __launch_bounds__(256) void scan_top_kernel(int* bsum, int nb)
{
    __shared__ int lds[256];
    const int tid = threadIdx.x;
    int v = (tid < nb) ? bsum[tid] : 0;
    lds[tid] = v;
    __syncthreads();
    for (int off = 1; off < 256; off <<= 1) {
        int t = (tid >= off) ? lds[tid - off] : 0;
        __syncthreads();
        lds[tid] += t;
        __syncthreads();
    }
    if (tid < nb) bsum[tid] = lds[tid] - v;
}

// ---- CSR build: add chunk offsets ----
__global__ __launch_bounds__(256) void scan_add_kernel(
    int* __restrict__ rowptr, int* __restrict__ cursor,
    const int* __restrict__ bsum, int N, int E)
{
    int i = blockIdx.x * blockDim.x + threadIdx.x;
    if (i < N) {
        int v = rowptr[i] + bsum[i >> 10];
        rowptr[i] = v;
        cursor[i] = v;
    }
    if (i == 0) rowptr[N] = E;
}

// ---- CSR build: bucket-fill sorted sender ids ----
__global__ __launch_bounds__(256) void fill_kernel(
    const int* __restrict__ senders, const int* __restrict__ receivers,
    int* __restrict__ cursor, int* __restrict__ ssend, int E)
{
    int e = blockIdx.x * blockDim.x + threadIdx.x;
    if (e < E) {
        int r = receivers[e];
        int pos = atomicAdd(&cursor[r], 1);
        ssend[pos] = senders[e];
    }
}

// ---- fused per-node attention (bf16 q) ----
__global__ __launch_bounds__(256) void node_attn_kernel(
    const unsigned short* __restrict__ q, const int* __restrict__ rowptr,
    const int* __restrict__ ssend, float* __restrict__ out, int N)
{
    const int lane = threadIdx.x & 63;
    const int hl   = lane & 31;
    const int half = lane >> 5;
    const int wid  = (blockIdx.x * blockDim.x + threadIdx.x) >> 6;
    const int nw   = (gridDim.x * blockDim.x) >> 6;

    for (int n = wid; n < N; n += nw) {
        const uint2 braw = *(const uint2*)&q[(size_t)n * D + hl * 4];
        const float b0 = __uint_as_float(braw.x << 16);
        const float b1 = __uint_as_float(braw.x & 0xffff0000u);
        const float b2 = __uint_as_float(braw.y << 16);
        const float b3 = __uint_as_float(braw.y & 0xffff0000u);

        const int beg = rowptr[n], end = rowptr[n + 1];
        float m = -1e30f, l = 0.f;
        float c0 = 0.f, c1 = 0.f, c2 = 0.f, c3 = 0.f;

        int j = beg + half;
        uint2 raw = {0u, 0u};
        if (j < end)
            raw = *(const uint2*)&q[(size_t)ssend[j] * D + hl * 4];
        for (; j < end; j += 2) {
            const uint2 cur = raw;
            if (j + 2 < end)
                raw = *(const uint2*)&q[(size_t)ssend[j + 2] * D + hl * 4];
            const float a0 = __uint_as_float(cur.x << 16);
            const float a1 = __uint_as_float(cur.x & 0xffff0000u);
            const float a2 = __uint_as_float(cur.y << 16);
            const float a3 = __uint_as_float(cur.y & 0xffff0000u);
            float p = a0 * b0 + a1 * b1 + a2 * b2 + a3 * b3;
            p += __shfl_xor(p, 1);
            p += __shfl_xor(p, 2);
            p += __shfl_xor(p, 4);
            const float logit = p * 0.17677669529663687f;   // 1/sqrt(32)
            const float nm = fmaxf(m, logit);
            const float sc = __expf(m - nm);
            const float u  = __expf(logit - nm);
            l  = l * sc + u;
            c0 = c0 * sc + u * a0;
            c1 = c1 * sc + u * a1;
            c2 = c2 * sc + u * a2;
            c3 = c3 * sc + u * a3;
            m = nm;
        }

        const float om  = __shfl_xor(m, 32);
        const float ol  = __shfl_xor(l, 32);
        const float oc0 = __shfl_xor(c0, 32);
        const float oc1 = __shfl_xor(c1, 32);
        const float oc2 = __shfl_xor(c2, 32);
        const float oc3 = __shfl_xor(c3, 32);
        const float nm = fmaxf(m, om);
        const float s0 = __expf(m - nm), s1 = __expf(om - nm);
        const float lt = l * s0 + ol * s1;
        const float inv = (lt > 0.f) ? (1.f / lt) : 0.f;
        float r0 = fmaxf((c0 * s0 + oc0 * s1) * inv, 0.f);
        float r1 = fmaxf((c1 * s0 + oc1 * s1) * inv, 0.f);
        float r2 = fmaxf((c2 * s0 + oc2 * s1) * inv, 0.f);
        float r3 = fmaxf((c3 * s0 + oc3 * s1) * inv, 0.f);

        r0 += __shfl_xor(r0, 8);  r0 += __shfl_xor(r0, 16);
        r1 += __shfl_xor(r1, 8);  r1 += __shfl_xor(r1, 16);
        r2 += __shfl_xor(r2, 8);  r2 += __shfl_xor(r2, 16);
        r3 += __shfl_xor(r3, 8);  r3 += __shfl_xor(r3, 16);
        if (lane < 8) {
            float4 o = {0.25f * r0, 0.25f * r1, 0.25f * r2, 0.25f * r3};
            *(float4*)&out[(size_t)n * NF + lane * 4] = o;
        }
    }
}

extern "C" void kernel_launch(void* const* d_in, const int* in_sizes, int n_in,
                              void* d_out, int out_size, void* d_ws, size_t ws_size,
                              hipStream_t stream)
{
    const float* nodes = (const float*)d_in[0];
    const float* W1    = (const float*)d_in[1];
    const float* b1    = (const float*)d_in[2];
    const float* g1    = (const float*)d_in[3];
    const float* be1   = (const float*)d_in[4];
    const float* W2    = (const float*)d_in[5];
    const float* b2    = (const float*)d_in[6];
    const float* g2    = (const float*)d_in[7];
    const float* be2   = (const float*)d_in[8];
    const int* senders   = (const int*)d_in[9];
    const int* receivers = (const int*)d_in[10];

    const int N = in_sizes[0] / D;
    const int E = in_sizes[9];
    float* out = (float*)d_out;

    char* ws = (char*)d_ws;
    unsigned short* qb = (unsigned short*)ws; ws += (size_t)N * D * 2;
    unsigned short* wt = (unsigned short*)ws; ws += 4 * 128 * 128 * 2;
    int* cnt      = (int*)ws;    ws += (size_t)N * 4;
    int* rowptr   = (int*)ws;    ws += (size_t)(N + 2) * 4;
    int* cursor   = (int*)ws;    ws += (size_t)N * 4;
    int* bsum     = (int*)ws;    ws += 256 * 4;
    int* ssend    = (int*)ws;    ws += (size_t)E * 4;

    zero_cnt_kernel<<<(N / 4 + 255) / 256, 256, 0, stream>>>(cnt, N);

    // weight split (fragment-ordered hi/lo), then pipelined MFMA MLP
    wsplit_kernel<<<16, 256, 0, stream>>>(W1, W2, wt);
    const int nwt = (N + 15) / 16;
    mlp_pipe_kernel<<<(nwt + 3) / 4, 256, 0, stream>>>(
        nodes, wt, b1, g1, be1, b2, g2, be2, qb, N);

    // CSR build (receiver-sorted sender list)
    const int nb = (N + 1023) / 1024;
    hist_kernel<<<(E + 255) / 256, 256, 0, stream>>>(receivers, cnt, E);
    scan_blocks_kernel<<<nb, 256, 0, stream>>>(cnt, rowptr, bsum, N);
    scan_top_kernel<<<1, 256, 0, stream>>>(bsum, nb);
    scan_add_kernel<<<(N + 255) / 256, 256, 0, stream>>>(rowptr, cursor, bsum, N, E);
    fill_kernel<<<(E + 255) / 256, 256, 0, stream>>>(senders, receivers, cursor, ssend, E);

    // fused attention + epilogue
    node_attn_kernel<<<(N + 3) / 4, 256, 0, stream>>>(qb, rowptr, ssend, out, N);
}

// Round 10
// 116.309 us; speedup vs baseline: 1.3540x; 1.1446x over previous
//
#include <hip/hip_runtime.h>

constexpr int D  = 128;   // feature dim (= H*F)
constexpr int NH = 4;     // heads
constexpr int NF = 32;    // features per head

typedef __attribute__((ext_vector_type(8))) short bfrag;   // 8 bf16 = 4 VGPR
typedef __attribute__((ext_vector_type(4))) float ffrag;   // 4 f32 acc

// bf16 RNE helpers
__device__ __forceinline__ unsigned short bf16h(float x) {
    unsigned u = __float_as_uint(x);
    u += 0x7fffu + ((u >> 16) & 1u);
    return (unsigned short)(u >> 16);
}
__device__ __forceinline__ float bf16tof(unsigned short h) {
    return __uint_as_float(((unsigned)h) << 16);
}

// ---- launch 1: wsplit (blocks 0..15) + zero counters (blocks 16..) ----
// wsplit output: 1KB chunks indexed ((L*2+plane)*32 + ctg*4 + ks); chunk[lane][i]
// = plane(W[ks*32 + (lane>>4)*8 + i][ctg*16 + (lane&15)]). A B-frag load is one
// coalesced global_load_dwordx4 at chunkbase + lane*16B.
__global__ __launch_bounds__(256) void prep_kernel(
    const float* __restrict__ W1, const float* __restrict__ W2,
    unsigned short* __restrict__ wt, int* __restrict__ cnt, int nz)
{
    if (blockIdx.x < 16) {
        const int L  = blockIdx.x >> 3;
        const int ct = blockIdx.x & 7;
        const float* W = L ? W2 : W1;
        const int ks   = threadIdx.x >> 6;
        const int lane = threadIdx.x & 63;
        const int lg = lane >> 4, lc = lane & 15;
        unsigned short* Hp = wt + ((size_t)(L * 2 + 0) * 32 + ct * 4 + ks) * 512 + lane * 8;
        unsigned short* Lp = wt + ((size_t)(L * 2 + 1) * 32 + ct * 4 + ks) * 512 + lane * 8;
        #pragma unroll
        for (int i = 0; i < 8; ++i) {
            const int k = ks * 32 + lg * 8 + i;
            const int c = ct * 16 + lc;
            const float v = W[(size_t)k * 128 + c];
            const unsigned short hh = bf16h(v);
            Hp[i] = hh;
            Lp[i] = bf16h(v - bf16tof(hh));
        }
    } else {
        const int i4 = ((blockIdx.x - 16) * 256 + threadIdx.x) * 4;
        if (i4 + 3 < nz) {
            *(int4*)&cnt[i4] = {0, 0, 0, 0};
        } else if (i4 < nz) {
            for (int i = i4; i < nz; ++i) cnt[i] = 0;
        }
    }
}

// ---- launch 2: MFMA MLP, 32 rows/wave (2 tiles share B) + histogram tail ----
// R9 post-mortem: hipcc always re-serializes B handling (~6.6Kcy per 8-load
// batch, 16 batches/wave). Can't fix the shape -> halve the batches per unit
// work: each wave owns TWO 16-row tiles that share every B-fragment. 1563
// waves x 16 batches (was 3125 x 16). A 64 + acc 64 + B 64 regs ~ 220 < 256.
__global__ __launch_bounds__(256, 2) void mlp_hist_kernel(
    const float* __restrict__ X,
    const unsigned short* __restrict__ WF,
    const float* __restrict__ b1, const float* __restrict__ g1, const float* __restrict__ be1,
    const float* __restrict__ b2, const float* __restrict__ g2, const float* __restrict__ be2,
    unsigned short* __restrict__ Q, int N,
    const int* __restrict__ recv, int* __restrict__ cnt, int E, int mlpBlocks)
{
    constexpr int PW = 132;                    // u32 pitch (528B, b128-aligned)
    __shared__ unsigned HL[4 * 2 * 16 * PW];   // 67584 B: [wave][tile][row][k]

    if (blockIdx.x >= mlpBlocks) {
        // ---- histogram role (runs as CUs free up) ----
        const int tid0   = (blockIdx.x - mlpBlocks) * 256 + threadIdx.x;
        const int stride = (gridDim.x - mlpBlocks) * 256;
        for (int i = tid0; i < E; i += stride) atomicAdd(&cnt[recv[i]], 1);
        return;
    }

    const int tid  = threadIdx.x;
    const int lane = tid & 63;
    const int wave = tid >> 6;
    const int lc   = lane & 15;
    const int lg   = lane >> 4;
    const int n0w  = (blockIdx.x * 4 + wave) * 32;   // 32 rows per wave
    if (n0w >= N) return;
    unsigned* hl0 = &HL[(wave * 2 + 0) * 16 * PW];
    unsigned* hl1 = &HL[(wave * 2 + 1) * 16 * PW];

    bfrag ah0[4], al0[4], ah1[4], al1[4];

    // ---- A-frags layer 1 for both tiles: from global X, split in-reg ----
    #pragma unroll
    for (int t = 0; t < 2; ++t) {
        const int row = n0w + t * 16 + lc;
        const int rowx = (row < N) ? row : (N - 1);
        const float* xr = X + (size_t)rowx * 128 + lg * 8;
        #pragma unroll
        for (int ks = 0; ks < 4; ++ks) {
            const float4 a = *(const float4*)&xr[ks * 32];
            const float4 b = *(const float4*)&xr[ks * 32 + 4];
            const float f[8] = {a.x, a.y, a.z, a.w, b.x, b.y, b.z, b.w};
            #pragma unroll
            for (int i = 0; i < 8; ++i) {
                const unsigned short hh = bf16h(f[i]);
                const unsigned short ll = bf16h(f[i] - bf16tof(hh));
                if (t == 0) { ah0[ks][i] = (short)hh; al0[ks][i] = (short)ll; }
                else        { ah1[ks][i] = (short)hh; al1[ks][i] = (short)ll; }
            }
        }
    }

    bfrag Bh0[4], Bl0[4], Bh1[4], Bl1[4];      // two B buffers (32 VGPR each)
    ffrag acc0[8], acc1[8];

#define LOADB(BH, BL, hiBase, loBase, ctg)                                     \
    {                                                                          \
        const unsigned short* hp_ = WF + (size_t)((hiBase) + (ctg) * 4) * 512 + lane * 8; \
        const unsigned short* lp_ = WF + (size_t)((loBase) + (ctg) * 4) * 512 + lane * 8; \
        _Pragma("unroll")                                                      \
        for (int ks_ = 0; ks_ < 4; ++ks_) {                                    \
            BH[ks_] = *(const bfrag*)(hp_ + ks_ * 512);                        \
            BL[ks_] = *(const bfrag*)(lp_ + ks_ * 512);                        \
        }                                                                      \
    }

#define COMPB2(BH, BL, d0, d1)                                                 \
    {                                                                          \
        ffrag aH0_ = (ffrag){0.f,0.f,0.f,0.f}, aX0_ = (ffrag){0.f,0.f,0.f,0.f};\
        ffrag aH1_ = (ffrag){0.f,0.f,0.f,0.f}, aX1_ = (ffrag){0.f,0.f,0.f,0.f};\
        _Pragma("unroll")                                                      \
        for (int ks_ = 0; ks_ < 4; ++ks_) {                                    \
            aH0_ = __builtin_amdgcn_mfma_f32_16x16x32_bf16(ah0[ks_], BH[ks_], aH0_, 0, 0, 0); \
            aH1_ = __builtin_amdgcn_mfma_f32_16x16x32_bf16(ah1[ks_], BH[ks_], aH1_, 0, 0, 0); \
            aX0_ = __builtin_amdgcn_mfma_f32_16x16x32_bf16(ah0[ks_], BL[ks_], aX0_, 0, 0, 0); \
            aX1_ = __builtin_amdgcn_mfma_f32_16x16x32_bf16(ah1[ks_], BL[ks_], aX1_, 0, 0, 0); \
            aX0_ = __builtin_amdgcn_mfma_f32_16x16x32_bf16(al0[ks_], BH[ks_], aX0_, 0, 0, 0); \
            aX1_ = __builtin_amdgcn_mfma_f32_16x16x32_bf16(al1[ks_], BH[ks_], aX1_, 0, 0, 0); \
        }                                                                      \
        d0 = aH0_ + aX0_;                                                      \
        d1 = aH1_ + aX1_;                                                      \
    }

#define GEMM_LAYER(hiBase, loBase)                                             \
    LOADB(Bh0, Bl0, hiBase, loBase, 0)                                         \
    LOADB(Bh1, Bl1, hiBase, loBase, 1)                                         \
    __builtin_amdgcn_sched_barrier(0);                                         \
    COMPB2(Bh0, Bl0, acc0[0], acc1[0])                                         \
    LOADB(Bh0, Bl0, hiBase, loBase, 2)                                         \
    __builtin_amdgcn_sched_barrier(0);                                         \
    COMPB2(Bh1, Bl1, acc0[1], acc1[1])                                         \
    LOADB(Bh1, Bl1, hiBase, loBase, 3)                                         \
    __builtin_amdgcn_sched_barrier(0);                                         \
    COMPB2(Bh0, Bl0, acc0[2], acc1[2])                                         \
    LOADB(Bh0, Bl0, hiBase, loBase, 4)                                         \
    __builtin_amdgcn_sched_barrier(0);                                         \
    COMPB2(Bh1, Bl1, acc0[3], acc1[3])                                         \
    LOADB(Bh1, Bl1, hiBase, loBase, 5)                                         \
    __builtin_amdgcn_sched_barrier(0);                                         \
    COMPB2(Bh0, Bl0, acc0[4], acc1[4])                                         \
    LOADB(Bh0, Bl0, hiBase, loBase, 6)                                         \
    __builtin_amdgcn_sched_barrier(0);                                         \
    COMPB2(Bh1, Bl1, acc0[5], acc1[5])                                         \
    LOADB(Bh1, Bl1, hiBase, loBase, 7)                                         \
    __builtin_amdgcn_sched_barrier(0);                                         \
    COMPB2(Bh0, Bl0, acc0[6], acc1[6])                                         \
    COMPB2(Bh1, Bl1, acc0[7], acc1[7])

// LN1 + ReLU over one tile's acc -> packed hi|lo u32 into tile scratch
#define LN1_TILE(ACC, HLP)                                                     \
    {                                                                          \
        _Pragma("unroll")                                                      \
        for (int j = 0; j < 4; ++j) {                                          \
            float t_[8], s_ = 0.f, ss_ = 0.f;                                  \
            _Pragma("unroll")                                                  \
            for (int ct = 0; ct < 8; ++ct) {                                   \
                t_[ct] = ACC[ct][j] + b1v[ct];                                 \
                s_ += t_[ct]; ss_ += t_[ct] * t_[ct];                          \
            }                                                                  \
            _Pragma("unroll")                                                  \
            for (int off = 1; off <= 8; off <<= 1) {                           \
                s_  += __shfl_xor(s_,  off, 16);                               \
                ss_ += __shfl_xor(ss_, off, 16);                               \
            }                                                                  \
            const float mu_   = s_ * (1.f / 128.f);                            \
            const float var_  = fmaxf(ss_ * (1.f / 128.f) - mu_ * mu_, 0.f);   \
            const float rstd_ = rsqrtf(var_ + 1e-6f);                          \
            const int row_ = lg * 4 + j;                                       \
            _Pragma("unroll")                                                  \
            for (int ct = 0; ct < 8; ++ct) {                                   \
                const float o_ = fmaxf((t_[ct] - mu_) * rstd_ * g1v[ct] + t1v[ct], 0.f); \
                const unsigned short hh_ = bf16h(o_);                          \
                const unsigned short ll_ = bf16h(o_ - bf16tof(hh_));           \
                HLP[row_ * PW + ct * 16 + lc] = (unsigned)hh_ | ((unsigned)ll_ << 16); \
            }                                                                  \
        }                                                                      \
    }

// reload one tile's A-frags from its scratch (row = lc, k = ks*32+lg*8+i)
#define LOADA2(AH, AL, HLP)                                                    \
    _Pragma("unroll")                                                          \
    for (int ks_ = 0; ks_ < 4; ++ks_) {                                        \
        const uint4 r0_ = *(const uint4*)&HLP[lc * PW + ks_ * 32 + lg * 8];    \
        const uint4 r1_ = *(const uint4*)&HLP[lc * PW + ks_ * 32 + lg * 8 + 4];\
        const unsigned rr_[8] = {r0_.x, r0_.y, r0_.z, r0_.w,                   \
                                 r1_.x, r1_.y, r1_.z, r1_.w};                  \
        _Pragma("unroll")                                                      \
        for (int i_ = 0; i_ < 8; ++i_) {                                       \
            AH[ks_][i_] = (short)(rr_[i_] & 0xffffu);                          \
            AL[ks_][i_] = (short)(rr_[i_] >> 16);                              \
        }                                                                      \
    }

// LN2 + ReLU over one tile's acc -> bf16 q rows at ROWBASE
#define LN2_TILE(ACC, ROWBASE)                                                 \
    {                                                                          \
        _Pragma("unroll")                                                      \
        for (int j = 0; j < 4; ++j) {                                          \
            float t_[8], s_ = 0.f, ss_ = 0.f;                                  \
            _Pragma("unroll")                                                  \
            for (int ct = 0; ct < 8; ++ct) {                                   \
                t_[ct] = ACC[ct][j] + b2v[ct];                                 \
                s_ += t_[ct]; ss_ += t_[ct] * t_[ct];                          \
            }                                                                  \
            _Pragma("unroll")                                                  \
            for (int off = 1; off <= 8; off <<= 1) {                           \
                s_  += __shfl_xor(s_,  off, 16);                               \
                ss_ += __shfl_xor(ss_, off, 16);                               \
            }                                                                  \
            const float mu_   = s_ * (1.f / 128.f);                            \
            const float var_  = fmaxf(ss_ * (1.f / 128.f) - mu_ * mu_, 0.f);   \
            const float rstd_ = rsqrtf(var_ + 1e-6f);                          \
            const int grow_ = (ROWBASE) + lg * 4 + j;                          \
            if (grow_ < N) {                                                   \
                _Pragma("unroll")                                              \
                for (int ct = 0; ct < 8; ++ct) {                               \
                    const float o_ = fmaxf((t_[ct] - mu_) * rstd_ * g2v[ct] + t2v[ct], 0.f); \
                    Q[(size_t)grow_ * 128 + ct * 16 + lc] = bf16h(o_);         \
                }                                                              \
            }                                                                  \
        }                                                                      \
    }

    // ---- hoist LN params ----
    float b1v[8], g1v[8], t1v[8], b2v[8], g2v[8], t2v[8];
    #pragma unroll
    for (int ct = 0; ct < 8; ++ct) {
        const int col = ct * 16 + lc;
        b1v[ct] = b1[col]; g1v[ct] = g1[col]; t1v[ct] = be1[col];
        b2v[ct] = b2[col]; g2v[ct] = g2[col]; t2v[ct] = be2[col];
    }

    // ================= layer 1 =================
    GEMM_LAYER(0, 32)

    LN1_TILE(acc0, hl0)
    LN1_TILE(acc1, hl1)

    // wave-local fence: all lanes' LDS writes complete before cross-lane reads
    asm volatile("s_waitcnt lgkmcnt(0)" ::: "memory");
    __builtin_amdgcn_sched_barrier(0);

    LOADA2(ah0, al0, hl0)
    LOADA2(ah1, al1, hl1)

    // ================= layer 2 =================
    GEMM_LAYER(64, 96)

    LN2_TILE(acc0, n0w)
    LN2_TILE(acc1, n0w + 16)

#undef LN2_TILE
#undef LOADA2
#undef LN1_TILE
#undef GEMM_LAYER
#undef COMPB2
#undef LOADB
}

// ---- CSR build: per-1024-chunk exclusive scan ----
__global__ __launch_bounds__(256) void scan_blocks_kernel(
    const int* __restrict__ cnt, int* __restrict__ rowptr,
    int* __restrict__ bsum, int N)
{
    __shared__ int lds[256];
    const int tid = threadIdx.x;
    const int base = blockIdx.x * 1024 + tid * 4;
    int v0 = (base + 0 < N) ? cnt[base + 0] : 0;
    int v1 = (base + 1 < N) ? cnt[base + 1] : 0;
    int v2 = (base + 2 < N) ? cnt[base + 2] : 0;
    int v3 = (base + 3 < N) ? cnt[base + 3] : 0;
    const int tsum = v0 + v1 + v2 + v3;
    lds[tid] = tsum;
    __syncthreads();
    for (int off = 1; off < 256; off <<= 1) {
        int t = (tid >= off) ? lds[tid - off] : 0;
        __syncthreads();
        lds[tid] += t;
        __syncthreads();
    }
    int run = lds[tid] - tsum;
    if (base + 0 < N) rowptr[base + 0] = run;
    run += v0;
    if (base + 1 < N) rowptr[base + 1] = run;
    run += v1;
    if (base + 2 < N) rowptr[base + 2] = run;
    run += v2;
    if (base + 3 < N) rowptr[base + 3] = run;
    if (tid == 255) bsum[blockIdx.x] = lds[255];
}

// ---- CSR build: scan block sums ----
__global__ __launch_bounds__(256) void scan_top_kernel(int* bsum, int nb)
{
    __shared__ int lds[256];
    const int tid = threadIdx.x;
    int v = (tid < nb) ? bsum[tid] : 0;
    lds[tid] = v;
    __syncthreads();
    for (int off = 1; off < 256; off <<= 1) {
        int t = (tid >= off) ? lds[tid - off] : 0;
        __syncthreads();
        lds[tid] += t;
        __syncthreads();
    }
    if (tid < nb) bsum[tid] = lds[tid] - v;
}

// ---- CSR build: add chunk offsets ----
__global__ __launch_bounds__(256) void scan_add_kernel(
    int* __restrict__ rowptr, int* __restrict__ cursor,
    const int* __restrict__ bsum, int N, int E)
{
    int i = blockIdx.x * blockDim.x + threadIdx.x;
    if (i < N) {
        int v = rowptr[i] + bsum[i >> 10];
        rowptr[i] = v;
        cursor[i] = v;
    }
    if (i == 0) rowptr[N] = E;
}

// ---- CSR build: bucket-fill sorted sender ids ----
__global__ __launch_bounds__(256) void fill_kernel(
    const int* __restrict__ senders, const int* __restrict__ receivers,
    int* __restrict__ cursor, int* __restrict__ ssend, int E)
{
    int e = blockIdx.x * blockDim.x + threadIdx.x;
    if (e < E) {
        int r = receivers[e];
        int pos = atomicAdd(&cursor[r], 1);
        ssend[pos] = senders[e];
    }
}

// ---- fused per-node attention (bf16 q) ----
__global__ __launch_bounds__(256) void node_attn_kernel(
    const unsigned short* __restrict__ q, const int* __restrict__ rowptr,
    const int* __restrict__ ssend, float* __restrict__ out, int N)
{
    const int lane = threadIdx.x & 63;
    const int hl   = lane & 31;
    const int half = lane >> 5;
    const int wid  = (blockIdx.x * blockDim.x + threadIdx.x) >> 6;
    const int nw   = (gridDim.x * blockDim.x) >> 6;

    for (int n = wid; n < N; n += nw) {
        const uint2 braw = *(const uint2*)&q[(size_t)n * D + hl * 4];
        const float b0 = __uint_as_float(braw.x << 16);
        const float b1 = __uint_as_float(braw.x & 0xffff0000u);
        const float b2 = __uint_as_float(braw.y << 16);
        const float b3 = __uint_as_float(braw.y & 0xffff0000u);

        const int beg = rowptr[n], end = rowptr[n + 1];
        float m = -1e30f, l = 0.f;
        float c0 = 0.f, c1 = 0.f, c2 = 0.f, c3 = 0.f;

        int j = beg + half;
        uint2 raw = {0u, 0u};
        if (j < end)
            raw = *(const uint2*)&q[(size_t)ssend[j] * D + hl * 4];
        for (; j < end; j += 2) {
            const uint2 cur = raw;
            if (j + 2 < end)
                raw = *(const uint2*)&q[(size_t)ssend[j + 2] * D + hl * 4];
            const float a0 = __uint_as_float(cur.x << 16);
            const float a1 = __uint_as_float(cur.x & 0xffff0000u);
            const float a2 = __uint_as_float(cur.y << 16);
            const float a3 = __uint_as_float(cur.y & 0xffff0000u);
            float p = a0 * b0 + a1 * b1 + a2 * b2 + a3 * b3;
            p += __shfl_xor(p, 1);
            p += __shfl_xor(p, 2);
            p += __shfl_xor(p, 4);
            const float logit = p * 0.17677669529663687f;   // 1/sqrt(32)
            const float nm = fmaxf(m, logit);
            const float sc = __expf(m - nm);
            const float u  = __expf(logit - nm);
            l  = l * sc + u;
            c0 = c0 * sc + u * a0;
            c1 = c1 * sc + u * a1;
            c2 = c2 * sc + u * a2;
            c3 = c3 * sc + u * a3;
            m = nm;
        }

        const float om  = __shfl_xor(m, 32);
        const float ol  = __shfl_xor(l, 32);
        const float oc0 = __shfl_xor(c0, 32);
        const float oc1 = __shfl_xor(c1, 32);
        const float oc2 = __shfl_xor(c2, 32);
        const float oc3 = __shfl_xor(c3, 32);
        const float nm = fmaxf(m, om);
        const float s0 = __expf(m - nm), s1 = __expf(om - nm);
        const float lt = l * s0 + ol * s1;
        const float inv = (lt > 0.f) ? (1.f / lt) : 0.f;
        float r0 = fmaxf((c0 * s0 + oc0 * s1) * inv, 0.f);
        float r1 = fmaxf((c1 * s0 + oc1 * s1) * inv, 0.f);
        float r2 = fmaxf((c2 * s0 + oc2 * s1) * inv, 0.f);
        float r3 = fmaxf((c3 * s0 + oc3 * s1) * inv, 0.f);

        r0 += __shfl_xor(r0, 8);  r0 += __shfl_xor(r0, 16);
        r1 += __shfl_xor(r1, 8);  r1 += __shfl_xor(r1, 16);
        r2 += __shfl_xor(r2, 8);  r2 += __shfl_xor(r2, 16);
        r3 += __shfl_xor(r3, 8);  r3 += __shfl_xor(r3, 16);
        if (lane < 8) {
            float4 o = {0.25f * r0, 0.25f * r1, 0.25f * r2, 0.25f * r3};
            *(float4*)&out[(size_t)n * NF + lane * 4] = o;
        }
    }
}

extern "C" void kernel_launch(void* const* d_in, const int* in_sizes, int n_in,
                              void* d_out, int out_size, void* d_ws, size_t ws_size,
                              hipStream_t stream)
{
    const float* nodes = (const float*)d_in[0];
    const float* W1    = (const float*)d_in[1];
    const float* b1    = (const float*)d_in[2];
    const float* g1    = (const float*)d_in[3];
    const float* be1   = (const float*)d_in[4];
    const float* W2    = (const float*)d_in[5];
    const float* b2    = (const float*)d_in[6];
    const float* g2    = (const float*)d_in[7];
    const float* be2   = (const float*)d_in[8];
    const int* senders   = (const int*)d_in[9];
    const int* receivers = (const int*)d_in[10];

    const int N = in_sizes[0] / D;
    const int E = in_sizes[9];
    float* out = (float*)d_out;

    char* ws = (char*)d_ws;
    unsigned short* qb = (unsigned short*)ws; ws += (size_t)N * D * 2;
    unsigned short* wt = (unsigned short*)ws; ws += 4 * 128 * 128 * 2;
    int* cnt      = (int*)ws;    ws += (size_t)N * 4;
    int* rowptr   = (int*)ws;    ws += (size_t)(N + 2) * 4;
    int* cursor   = (int*)ws;    ws += (size_t)N * 4;
    int* bsum     = (int*)ws;    ws += 256 * 4;
    int* ssend    = (int*)ws;    ws += (size_t)E * 4;

    const int zb = (N + 1023) / 1024;
    const int nwt32 = (N + 31) / 32;
    const int mlpBlocks = (nwt32 + 3) / 4;
    const int nb = (N + 1023) / 1024;

    // 1: weight split + counter zero
    prep_kernel<<<16 + zb, 256, 0, stream>>>(W1, W2, wt, cnt, N);

    // 2: 32-rows/wave MFMA MLP + edge histogram (tail blocks)
    mlp_hist_kernel<<<mlpBlocks + 128, 256, 0, stream>>>(
        nodes, wt, b1, g1, be1, b2, g2, be2, qb, N,
        receivers, cnt, E, mlpBlocks);

    // 3-5: CSR scan (R4-proven 3-kernel structure)
    scan_blocks_kernel<<<nb, 256, 0, stream>>>(cnt, rowptr, bsum, N);
    scan_top_kernel<<<1, 256, 0, stream>>>(bsum, nb);
    scan_add_kernel<<<(N + 255) / 256, 256, 0, stream>>>(rowptr, cursor, bsum, N, E);

    // 6: bucket-fill receiver-sorted sender list
    fill_kernel<<<(E + 255) / 256, 256, 0, stream>>>(senders, receivers, cursor, ssend, E);

    // 7: fused attention + epilogue
    node_attn_kernel<<<(N + 3) / 4, 256, 0, stream>>>(qb, rowptr, ssend, out, N);
}